// Round 1
// baseline (648.398 us; speedup 1.0000x reference)
//
#include <hip/hip_runtime.h>
#include <math.h>

#define D_IN 256
#define HID 128
#define D_OUT 64
#define NEG_SLOPE 0.2f

__device__ __forceinline__ float wave_reduce_sum(float v) {
    #pragma unroll
    for (int off = 32; off > 0; off >>= 1) v += __shfl_xor(v, off, 64);
    return v;
}
__device__ __forceinline__ float wave_reduce_max(float v) {
    #pragma unroll
    for (int off = 32; off > 0; off >>= 1) v = fmaxf(v, __shfl_xor(v, off, 64));
    return v;
}

// ---- tiny prep: v_src/v_dst GEMV weights (W @ att), combined layer-2 bias ----
__global__ void prep_kernel(const float* __restrict__ Wsrc1, const float* __restrict__ att_src1,
                            const float* __restrict__ Wdst1, const float* __restrict__ att_dst1,
                            const float* __restrict__ Wsrc2, const float* __restrict__ att_src2,
                            const float* __restrict__ Wdst2, const float* __restrict__ att_dst2,
                            const float* __restrict__ b2, const float* __restrict__ b_lin2,
                            float* v_src1, float* v_dst1, float* v_src2, float* v_dst2,
                            float* bsum2) {
    int t = threadIdx.x;
    if (t < D_IN) {
        float s1 = 0.f, s2 = 0.f;
        for (int c = 0; c < HID; c++) {
            s1 += Wsrc1[t * HID + c] * att_src1[c];
            s2 += Wdst1[t * HID + c] * att_dst1[c];
        }
        v_src1[t] = s1; v_dst1[t] = s2;
    }
    if (t < HID) {
        float s1 = 0.f, s2 = 0.f;
        for (int c = 0; c < D_OUT; c++) {
            s1 += Wsrc2[t * D_OUT + c] * att_src2[c];
            s2 += Wdst2[t * D_OUT + c] * att_dst2[c];
        }
        v_src2[t] = s1; v_dst2[t] = s2;
    }
    if (t < D_OUT) bsum2[t] = b2[t] + b_lin2[t];
}

// ---- CSR build: histogram -> exclusive scan -> scatter ----
__global__ void hist_kernel(const int* __restrict__ dst, int E, int* deg) {
    int e = blockIdx.x * 256 + threadIdx.x;
    if (e < E) atomicAdd(&deg[dst[e]], 1);
}

__global__ void scan_kernel(const int* __restrict__ deg, int* row_ptr, int* cursor, int n) {
    __shared__ int sdata[1024];
    __shared__ int s_carry;
    int tid = threadIdx.x;
    if (tid == 0) s_carry = 0;
    __syncthreads();
    for (int base = 0; base < n; base += 1024) {
        int i = base + tid;
        int v = (i < n) ? deg[i] : 0;
        sdata[tid] = v;
        __syncthreads();
        for (int off = 1; off < 1024; off <<= 1) {
            int t = (tid >= off) ? sdata[tid - off] : 0;
            __syncthreads();
            sdata[tid] += t;
            __syncthreads();
        }
        int excl = s_carry + sdata[tid] - v;
        if (i < n) { row_ptr[i] = excl; cursor[i] = excl; }
        __syncthreads();
        if (tid == 0) s_carry += sdata[1023];
        __syncthreads();
    }
    if (tid == 0) row_ptr[n] = s_carry;
}

__global__ void scatter_kernel(const int* __restrict__ src, const int* __restrict__ dst, int E,
                               int* cursor, int* ssrc, int* seid) {
    int e = blockIdx.x * 256 + threadIdx.x;
    if (e < E) {
        int d = dst[e];
        int pos = atomicAdd(&cursor[d], 1);
        ssrc[pos] = src[e];
        seid[pos] = e;
    }
}

// ---- fp32 tiled GEMM: C[M,N] = A[M,K] @ B[K,N] (+bias), BM=BN=64, BK=32 ----
__global__ __launch_bounds__(256) void gemm_kernel(const float* __restrict__ A,
                                                   const float* __restrict__ B,
                                                   const float* __restrict__ bias,
                                                   float* __restrict__ C,
                                                   int M, int N, int K) {
    __shared__ float As[32][68];  // [k][row], stride 68 floats (16B-aligned rows, conflict-free)
    __shared__ float Bs[32][64];  // [k][col]
    int tid = threadIdx.x;
    int bm = blockIdx.x * 64, bn = blockIdx.y * 64;
    int ty = tid >> 4, tx = tid & 15;  // 16x16 threads, 4x4 micro-tile each

    float acc[4][4];
    #pragma unroll
    for (int i = 0; i < 4; i++)
        #pragma unroll
        for (int j = 0; j < 4; j++) acc[i][j] = 0.f;

    for (int k0 = 0; k0 < K; k0 += 32) {
        #pragma unroll
        for (int f = tid; f < 512; f += 256) {       // A tile: 64 rows x 8 float4
            int r = f >> 3, kg = f & 7;
            int gr = bm + r;
            float4 v = make_float4(0.f, 0.f, 0.f, 0.f);
            if (gr < M) v = *(const float4*)(A + (size_t)gr * K + k0 + kg * 4);
            As[kg * 4 + 0][r] = v.x; As[kg * 4 + 1][r] = v.y;
            As[kg * 4 + 2][r] = v.z; As[kg * 4 + 3][r] = v.w;
        }
        #pragma unroll
        for (int f = tid; f < 512; f += 256) {       // B tile: 32 k-rows x 16 float4
            int kr = f >> 4, ng = f & 15;
            *(float4*)&Bs[kr][ng * 4] = *(const float4*)(B + (size_t)(k0 + kr) * N + bn + ng * 4);
        }
        __syncthreads();
        #pragma unroll
        for (int k = 0; k < 32; k++) {
            float4 a = *(const float4*)&As[k][ty * 4];
            float4 b = *(const float4*)&Bs[k][tx * 4];
            float av[4] = {a.x, a.y, a.z, a.w};
            float bv[4] = {b.x, b.y, b.z, b.w};
            #pragma unroll
            for (int i = 0; i < 4; i++)
                #pragma unroll
                for (int j = 0; j < 4; j++) acc[i][j] += av[i] * bv[j];
        }
        __syncthreads();
    }

    float4 bv4 = make_float4(0.f, 0.f, 0.f, 0.f);
    if (bias) bv4 = *(const float4*)(bias + bn + tx * 4);
    #pragma unroll
    for (int i = 0; i < 4; i++) {
        int gr = bm + ty * 4 + i;
        if (gr < M) {
            float4 o = make_float4(acc[i][0] + bv4.x, acc[i][1] + bv4.y,
                                   acc[i][2] + bv4.z, acc[i][3] + bv4.w);
            *(float4*)(C + (size_t)gr * N + bn + tx * 4) = o;
        }
    }
}

// ---- per-node attention scalars: a_src[n] = x[n]·v_src, a_dst[n] = x[n]·v_dst ----
__global__ void akern(const float* __restrict__ X, const float* __restrict__ vsrc,
                      const float* __restrict__ vdst, float* a_src, float* a_dst,
                      int Nn, int K) {
    int node = blockIdx.x * 4 + (threadIdx.x >> 6);
    int lane = threadIdx.x & 63;
    if (node >= Nn) return;
    const float* row = X + (size_t)node * K;
    float s1 = 0.f, s2 = 0.f;
    for (int k = lane; k < K; k += 64) {
        float xv = row[k];
        s1 += xv * vsrc[k];
        s2 += xv * vdst[k];
    }
    s1 = wave_reduce_sum(s1);
    s2 = wave_reduce_sum(s2);
    if (lane == 0) { a_src[node] = s1; a_dst[node] = s2; }
}

// ---- layer-1 aggregation: one wave per dst node, exact segment softmax ----
__global__ void agg1_kernel(const int* __restrict__ row_ptr, const int* __restrict__ ssrc,
                            const float* __restrict__ a_src, const float* __restrict__ a_dst,
                            const float* __restrict__ h_src, const float* __restrict__ b1,
                            float* __restrict__ hbuf /* in: lin1+b_lin1, out: h */,
                            float* __restrict__ lbuf, int Nn) {
    int node = blockIdx.x * 4 + (threadIdx.x >> 6);
    int lane = threadIdx.x & 63;
    if (node >= Nn) return;
    int beg = row_ptr[node], end = row_ptr[node + 1];
    float ad = a_dst[node];

    float m = -INFINITY;
    for (int j = beg + lane; j < end; j += 64) {
        float l = a_src[ssrc[j]] + ad;
        l = (l > 0.f) ? l : NEG_SLOPE * l;
        lbuf[j] = l;
        m = fmaxf(m, l);
    }
    m = wave_reduce_max(m);

    float ssum = 0.f;
    for (int j = beg + lane; j < end; j += 64) {
        float e = __expf(lbuf[j] - m);
        lbuf[j] = e;
        ssum += e;
    }
    ssum = wave_reduce_sum(ssum);
    float inv = 1.f / (ssum + 1e-16f);

    float2 acc = make_float2(0.f, 0.f);
    for (int j = beg; j < end; j++) {
        float w = lbuf[j] * inv;                       // broadcast load
        const float2 hv = *(const float2*)(h_src + (size_t)ssrc[j] * HID + lane * 2);
        acc.x += w * hv.x; acc.y += w * hv.y;
    }
    float2 lin = *(const float2*)(hbuf + (size_t)node * HID + lane * 2);
    float2 o;
    o.x = fmaxf(acc.x + b1[lane * 2 + 0] + lin.x, 0.f);
    o.y = fmaxf(acc.y + b1[lane * 2 + 1] + lin.y, 0.f);
    *(float2*)(hbuf + (size_t)node * HID + lane * 2) = o;
}

// ---- layer-2 aggregation (+ alpha output) ----
__global__ void agg2_kernel(const int* __restrict__ row_ptr, const int* __restrict__ ssrc,
                            const int* __restrict__ seid,
                            const float* __restrict__ a_src, const float* __restrict__ a_dst,
                            const float* __restrict__ h_src2,
                            float* __restrict__ out /* in: lin2+b_lin2+b2 */,
                            float* __restrict__ alpha_out,
                            float* __restrict__ lbuf, int Nn) {
    int node = blockIdx.x * 4 + (threadIdx.x >> 6);
    int lane = threadIdx.x & 63;
    if (node >= Nn) return;
    int beg = row_ptr[node], end = row_ptr[node + 1];
    float ad = a_dst[node];

    float m = -INFINITY;
    for (int j = beg + lane; j < end; j += 64) {
        float l = a_src[ssrc[j]] + ad;
        l = (l > 0.f) ? l : NEG_SLOPE * l;
        lbuf[j] = l;
        m = fmaxf(m, l);
    }
    m = wave_reduce_max(m);

    float ssum = 0.f;
    for (int j = beg + lane; j < end; j += 64) {
        float e = __expf(lbuf[j] - m);
        lbuf[j] = e;
        ssum += e;
    }
    ssum = wave_reduce_sum(ssum);
    float inv = 1.f / (ssum + 1e-16f);

    for (int j = beg + lane; j < end; j += 64)
        alpha_out[seid[j]] = lbuf[j] * inv;

    float acc = 0.f;
    for (int j = beg; j < end; j++) {
        float w = lbuf[j] * inv;
        acc += w * h_src2[(size_t)ssrc[j] * D_OUT + lane];
    }
    float* orow = out + (size_t)node * D_OUT;
    orow[lane] = acc + orow[lane];
}

extern "C" void kernel_launch(void* const* d_in, const int* in_sizes, int n_in,
                              void* d_out, int out_size, void* d_ws, size_t ws_size,
                              hipStream_t stream) {
    const float* x        = (const float*)d_in[0];
    const int*   ei       = (const int*)d_in[1];
    const float* W_src1   = (const float*)d_in[2];
    const float* W_dst1   = (const float*)d_in[3];
    const float* att_src1 = (const float*)d_in[4];
    const float* att_dst1 = (const float*)d_in[5];
    const float* b1       = (const float*)d_in[6];
    const float* W_lin1   = (const float*)d_in[7];
    const float* b_lin1   = (const float*)d_in[8];
    const float* W_src2   = (const float*)d_in[9];
    const float* W_dst2   = (const float*)d_in[10];
    const float* att_src2 = (const float*)d_in[11];
    const float* att_dst2 = (const float*)d_in[12];
    const float* b2       = (const float*)d_in[13];
    const float* W_lin2   = (const float*)d_in[14];
    const float* b_lin2   = (const float*)d_in[15];

    const int Nn = in_sizes[0] / D_IN;   // 50000
    const int E  = in_sizes[1] / 2;      // 800000
    const int* src = ei;
    const int* dst = ei + E;

    // workspace carve (~76 MB)
    char* w = (char*)d_ws;
    auto alloc = [&](size_t bytes) { char* p = w; w += (bytes + 255) & ~(size_t)255; return p; };
    float* h_src1 = (float*)alloc((size_t)Nn * HID * 4);
    float* hbuf   = (float*)alloc((size_t)Nn * HID * 4);
    float* h_src2 = (float*)alloc((size_t)Nn * D_OUT * 4);
    float* lbuf   = (float*)alloc((size_t)E * 4);
    float* a_src1 = (float*)alloc((size_t)Nn * 4);
    float* a_dst1 = (float*)alloc((size_t)Nn * 4);
    float* a_src2 = (float*)alloc((size_t)Nn * 4);
    float* a_dst2 = (float*)alloc((size_t)Nn * 4);
    int*   deg    = (int*)alloc((size_t)Nn * 4);
    int*   row_ptr= (int*)alloc((size_t)(Nn + 1) * 4);
    int*   cursor = (int*)alloc((size_t)Nn * 4);
    int*   ssrc   = (int*)alloc((size_t)E * 4);
    int*   seid   = (int*)alloc((size_t)E * 4);
    float* v_src1 = (float*)alloc(D_IN * 4);
    float* v_dst1 = (float*)alloc(D_IN * 4);
    float* v_src2 = (float*)alloc(HID * 4);
    float* v_dst2 = (float*)alloc(HID * 4);
    float* bsum2  = (float*)alloc(D_OUT * 4);

    float* out       = (float*)d_out;
    float* alpha_out = out + (size_t)Nn * D_OUT;

    prep_kernel<<<1, 256, 0, stream>>>(W_src1, att_src1, W_dst1, att_dst1,
                                       W_src2, att_src2, W_dst2, att_dst2,
                                       b2, b_lin2, v_src1, v_dst1, v_src2, v_dst2, bsum2);

    hipMemsetAsync(deg, 0, (size_t)Nn * 4, stream);
    int eblocks = (E + 255) / 256;
    hist_kernel<<<eblocks, 256, 0, stream>>>(dst, E, deg);
    scan_kernel<<<1, 1024, 0, stream>>>(deg, row_ptr, cursor, Nn);
    scatter_kernel<<<eblocks, 256, 0, stream>>>(src, dst, E, cursor, ssrc, seid);

    int mblocks = (Nn + 63) / 64;
    dim3 g1(mblocks, HID / 64);
    gemm_kernel<<<g1, 256, 0, stream>>>(x, W_src1, nullptr, h_src1, Nn, HID, D_IN);
    gemm_kernel<<<g1, 256, 0, stream>>>(x, W_lin1, b_lin1, hbuf, Nn, HID, D_IN);

    int ablocks = (Nn + 3) / 4;
    akern<<<ablocks, 256, 0, stream>>>(x, v_src1, v_dst1, a_src1, a_dst1, Nn, D_IN);
    agg1_kernel<<<ablocks, 256, 0, stream>>>(row_ptr, ssrc, a_src1, a_dst1, h_src1, b1,
                                             hbuf, lbuf, Nn);

    dim3 g2(mblocks, D_OUT / 64);
    gemm_kernel<<<g2, 256, 0, stream>>>(hbuf, W_src2, nullptr, h_src2, Nn, D_OUT, HID);
    gemm_kernel<<<g2, 256, 0, stream>>>(hbuf, W_lin2, bsum2, out, Nn, D_OUT, HID);
    akern<<<ablocks, 256, 0, stream>>>(hbuf, v_src2, v_dst2, a_src2, a_dst2, Nn, HID);
    agg2_kernel<<<ablocks, 256, 0, stream>>>(row_ptr, ssrc, seid, a_src2, a_dst2, h_src2,
                                             out, alpha_out, lbuf, Nn);
}

// Round 2
// 431.270 us; speedup vs baseline: 1.5035x; 1.5035x over previous
//
#include <hip/hip_runtime.h>
#include <math.h>

#define D_IN 256
#define HID 128
#define D_OUT 64
#define NEG_SLOPE 0.2f

typedef short short8 __attribute__((ext_vector_type(8)));
typedef float floatx4 __attribute__((ext_vector_type(4)));

__device__ __forceinline__ float wave_reduce_sum(float v) {
    #pragma unroll
    for (int off = 32; off > 0; off >>= 1) v += __shfl_xor(v, off, 64);
    return v;
}
__device__ __forceinline__ float wave_reduce_max(float v) {
    #pragma unroll
    for (int off = 32; off > 0; off >>= 1) v = fmaxf(v, __shfl_xor(v, off, 64));
    return v;
}
__device__ __forceinline__ int wave_reduce_sum_i(int v) {
    #pragma unroll
    for (int off = 32; off > 0; off >>= 1) v += __shfl_xor(v, off, 64);
    return v;
}
__device__ __forceinline__ int wave_scan_incl_i(int v) {
    int lane = threadIdx.x & 63;
    #pragma unroll
    for (int off = 1; off < 64; off <<= 1) {
        int t = __shfl_up(v, off, 64);
        if (lane >= off) v += t;
    }
    return v;
}

__device__ __forceinline__ short f2bf(float f) {           // RNE f32->bf16
    unsigned u = __float_as_uint(f);
    u += 0x7fffu + ((u >> 16) & 1u);
    return (short)(u >> 16);
}
__device__ __forceinline__ float bflo(unsigned p) { return __uint_as_float(p << 16); }
__device__ __forceinline__ float bfhi(unsigned p) { return __uint_as_float(p & 0xffff0000u); }

// ---- prep: v_src/v_dst GEMV weights (W @ att), combined layer-2 bias ----
__global__ void prep_kernel(const float* __restrict__ Wsrc1, const float* __restrict__ att_src1,
                            const float* __restrict__ Wdst1, const float* __restrict__ att_dst1,
                            const float* __restrict__ Wsrc2, const float* __restrict__ att_src2,
                            const float* __restrict__ Wdst2, const float* __restrict__ att_dst2,
                            const float* __restrict__ b2, const float* __restrict__ b_lin2,
                            float* v_src1, float* v_dst1, float* v_src2, float* v_dst2,
                            float* bsum2) {
    int t = threadIdx.x;
    if (t < D_IN) {
        float s1 = 0.f, s2 = 0.f;
        for (int c = 0; c < HID; c++) {
            s1 += Wsrc1[t * HID + c] * att_src1[c];
            s2 += Wdst1[t * HID + c] * att_dst1[c];
        }
        v_src1[t] = s1; v_dst1[t] = s2;
    }
    if (t < HID) {
        float s1 = 0.f, s2 = 0.f;
        for (int c = 0; c < D_OUT; c++) {
            s1 += Wsrc2[t * D_OUT + c] * att_src2[c];
            s2 += Wdst2[t * D_OUT + c] * att_dst2[c];
        }
        v_src2[t] = s1; v_dst2[t] = s2;
    }
    if (t < D_OUT) bsum2[t] = b2[t] + b_lin2[t];
}

// ---- pack [Wa | Wb] (K x N each, fp32) into bf16 B-fragment layout ----
// Wp[((t*KS + s)*64 + lane)*8 + j] = W[k][n], k = s*32 + (lane>>4)*8 + j,
// n = (t % NTH)*16 + (lane&15); t < NTH -> Wa, else Wb.
__global__ void pack_kernel(const float* __restrict__ Wa, const float* __restrict__ Wb,
                            short* __restrict__ Wp, int KS, int NTH, int N) {
    int idx = blockIdx.x * 256 + threadIdx.x;
    int j = idx & 7;
    int lane = (idx >> 3) & 63;
    int rest = idx >> 9;
    int s = rest % KS;
    int t = rest / KS;
    if (t >= 2 * NTH) return;
    int k = s * 32 + ((lane >> 4) * 8) + j;
    int tt = (t < NTH) ? t : t - NTH;
    int n = tt * 16 + (lane & 15);
    const float* W = (t < NTH) ? Wa : Wb;
    Wp[idx] = f2bf(W[(size_t)k * N + n]);
}

// ---- CSR build ----
__global__ void hist_kernel(const int* __restrict__ dst, int E, int* deg) {
    int e = blockIdx.x * 256 + threadIdx.x;
    if (e < E) atomicAdd(&deg[dst[e]], 1);
}

__global__ void scan_partial(const int* __restrict__ deg, int n, int* bsums) {
    __shared__ int ws[16];
    int i = blockIdx.x * 1024 + threadIdx.x;
    int v = (i < n) ? deg[i] : 0;
    int s = wave_reduce_sum_i(v);
    if ((threadIdx.x & 63) == 0) ws[threadIdx.x >> 6] = s;
    __syncthreads();
    if (threadIdx.x == 0) {
        int tot = 0;
        #pragma unroll
        for (int w = 0; w < 16; w++) tot += ws[w];
        bsums[blockIdx.x] = tot;
    }
}

__global__ void scan_offsets(const int* __restrict__ bsums, int nb, int* boff) {
    int lane = threadIdx.x;
    int v = (lane < nb) ? bsums[lane] : 0;
    int incl = wave_scan_incl_i(v);
    if (lane < nb) boff[lane] = incl - v;
}

__global__ void scan_final(const int* __restrict__ deg, int n, const int* __restrict__ boff,
                           int* row_ptr, int* cursor) {
    __shared__ int ws[16];
    int i = blockIdx.x * 1024 + threadIdx.x;
    int wid = threadIdx.x >> 6;
    int v = (i < n) ? deg[i] : 0;
    int sv = wave_scan_incl_i(v);
    if ((threadIdx.x & 63) == 63) ws[wid] = sv;
    __syncthreads();
    if (threadIdx.x == 0) {
        int run = 0;
        #pragma unroll
        for (int w = 0; w < 16; w++) { int t = ws[w]; ws[w] = run; run += t; }
    }
    __syncthreads();
    int excl = boff[blockIdx.x] + ws[wid] + sv - v;
    if (i < n) {
        row_ptr[i] = excl; cursor[i] = excl;
        if (i == n - 1) row_ptr[n] = excl + v;
    }
}

__global__ void scatter_kernel(const int* __restrict__ src, const int* __restrict__ dst, int E,
                               int* cursor, int* ssrc, int* seid) {
    int e = blockIdx.x * 256 + threadIdx.x;
    if (e < E) {
        int d = dst[e];
        int pos = atomicAdd(&cursor[d], 1);
        ssrc[pos] = src[e];
        seid[pos] = e;
    }
}

// ---- fused MFMA GEMM: [outb | outf] = A @ [Wa | Wb]; A fp32 -> bf16 in-reg ----
// One wave per 16-row m-tile; NTH n-tiles per half; KS k-steps of 32.
// outb (first half) written bf16; outf (second half) written fp32 + bias.
template <int KS, int NTH>
__global__ __launch_bounds__(256) void gemm_fused(const float* __restrict__ A,
                                                  const short* __restrict__ Wp,
                                                  const float* __restrict__ bias,
                                                  unsigned short* __restrict__ outb,
                                                  float* __restrict__ outf, int M) {
    const int K = KS * 32, N = NTH * 16;
    int lane = threadIdx.x & 63;
    int mt = blockIdx.x * 4 + (threadIdx.x >> 6);
    if (mt * 16 >= M) return;
    int m0 = mt * 16, quad = lane >> 4, mr = lane & 15;
    const float* arow = A + (size_t)(m0 + mr) * K;

    floatx4 acc[2 * NTH];
    #pragma unroll
    for (int t = 0; t < 2 * NTH; t++) acc[t] = (floatx4){0.f, 0.f, 0.f, 0.f};

    #pragma unroll
    for (int s = 0; s < KS; s++) {
        const float* ap = arow + s * 32 + quad * 8;
        float4 a0 = *(const float4*)ap;
        float4 a1 = *(const float4*)(ap + 4);
        short8 af = {f2bf(a0.x), f2bf(a0.y), f2bf(a0.z), f2bf(a0.w),
                     f2bf(a1.x), f2bf(a1.y), f2bf(a1.z), f2bf(a1.w)};
        const short* wp = Wp + ((size_t)s * 64 + lane) * 8;
        #pragma unroll
        for (int t = 0; t < 2 * NTH; t++) {
            short8 bfr = *(const short8*)(wp + (size_t)t * KS * 512);
            acc[t] = __builtin_amdgcn_mfma_f32_16x16x32_bf16(af, bfr, acc[t], 0, 0, 0);
        }
    }
    #pragma unroll
    for (int t = 0; t < NTH; t++) {
        int col = t * 16 + mr;
        #pragma unroll
        for (int r = 0; r < 4; r++)
            outb[(size_t)(m0 + quad * 4 + r) * N + col] = (unsigned short)f2bf(acc[t][r]);
    }
    #pragma unroll
    for (int t = NTH; t < 2 * NTH; t++) {
        int col = (t - NTH) * 16 + mr;
        float b = bias ? bias[col] : 0.f;
        #pragma unroll
        for (int r = 0; r < 4; r++)
            outf[(size_t)(m0 + quad * 4 + r) * N + col] = acc[t][r] + b;
    }
}

// ---- per-node attention scalars ----
__global__ void akern(const float* __restrict__ X, const float* __restrict__ vsrc,
                      const float* __restrict__ vdst, float* a_src, float* a_dst,
                      int Nn, int K) {
    int node = blockIdx.x * 4 + (threadIdx.x >> 6);
    int lane = threadIdx.x & 63;
    if (node >= Nn) return;
    const float* row = X + (size_t)node * K;
    float s1 = 0.f, s2 = 0.f;
    for (int k = lane; k < K; k += 64) {
        float xv = row[k];
        s1 += xv * vsrc[k];
        s2 += xv * vdst[k];
    }
    s1 = wave_reduce_sum(s1);
    s2 = wave_reduce_sum(s2);
    if (lane == 0) { a_src[node] = s1; a_dst[node] = s2; }
}

// ---- layer-1 aggregation: wave per dst node, bf16 gather rows, 4x unroll ----
__global__ void agg1_kernel(const int* __restrict__ row_ptr, const int* __restrict__ ssrc,
                            const float* __restrict__ a_src, const float* __restrict__ a_dst,
                            const unsigned short* __restrict__ h1b, const float* __restrict__ b1,
                            const float* __restrict__ lin, float* __restrict__ hout,
                            float* __restrict__ lbuf, int Nn) {
    int node = blockIdx.x * 4 + (threadIdx.x >> 6);
    int lane = threadIdx.x & 63;
    if (node >= Nn) return;
    int beg = row_ptr[node], end = row_ptr[node + 1];
    float ad = a_dst[node];

    float m = -INFINITY;
    for (int j = beg + lane; j < end; j += 64) {
        float l = a_src[ssrc[j]] + ad;
        l = (l > 0.f) ? l : NEG_SLOPE * l;
        lbuf[j] = l;
        m = fmaxf(m, l);
    }
    m = wave_reduce_max(m);

    float ssum = 0.f;
    for (int j = beg + lane; j < end; j += 64) {
        float e = __expf(lbuf[j] - m);
        lbuf[j] = e;
        ssum += e;
    }
    ssum = wave_reduce_sum(ssum);
    float inv = 1.f / (ssum + 1e-16f);

    float ax0 = 0.f, ay0 = 0.f, ax1 = 0.f, ay1 = 0.f;
    int j = beg;
    for (; j + 3 < end; j += 4) {
        float w0 = lbuf[j] * inv, w1 = lbuf[j + 1] * inv;
        float w2 = lbuf[j + 2] * inv, w3 = lbuf[j + 3] * inv;
        int s0 = ssrc[j], s1 = ssrc[j + 1], s2 = ssrc[j + 2], s3 = ssrc[j + 3];
        unsigned p0 = *(const unsigned*)(h1b + (size_t)s0 * HID + lane * 2);
        unsigned p1 = *(const unsigned*)(h1b + (size_t)s1 * HID + lane * 2);
        unsigned p2 = *(const unsigned*)(h1b + (size_t)s2 * HID + lane * 2);
        unsigned p3 = *(const unsigned*)(h1b + (size_t)s3 * HID + lane * 2);
        ax0 += w0 * bflo(p0); ay0 += w0 * bfhi(p0);
        ax1 += w1 * bflo(p1); ay1 += w1 * bfhi(p1);
        ax0 += w2 * bflo(p2); ay0 += w2 * bfhi(p2);
        ax1 += w3 * bflo(p3); ay1 += w3 * bfhi(p3);
    }
    for (; j < end; j++) {
        float w = lbuf[j] * inv;
        unsigned p = *(const unsigned*)(h1b + (size_t)ssrc[j] * HID + lane * 2);
        ax0 += w * bflo(p); ay0 += w * bfhi(p);
    }
    int c = lane * 2;
    const float* lrow = lin + (size_t)node * HID;
    float* orow = hout + (size_t)node * HID;
    orow[c + 0] = fmaxf(ax0 + ax1 + b1[c + 0] + lrow[c + 0], 0.f);
    orow[c + 1] = fmaxf(ay0 + ay1 + b1[c + 1] + lrow[c + 1], 0.f);
}

// ---- layer-2 aggregation (+ alpha output), bf16 gather rows ----
__global__ void agg2_kernel(const int* __restrict__ row_ptr, const int* __restrict__ ssrc,
                            const int* __restrict__ seid,
                            const float* __restrict__ a_src, const float* __restrict__ a_dst,
                            const unsigned short* __restrict__ h2b,
                            float* __restrict__ out, float* __restrict__ alpha_out,
                            float* __restrict__ lbuf, int Nn) {
    int node = blockIdx.x * 4 + (threadIdx.x >> 6);
    int lane = threadIdx.x & 63;
    if (node >= Nn) return;
    int beg = row_ptr[node], end = row_ptr[node + 1];
    float ad = a_dst[node];

    float m = -INFINITY;
    for (int j = beg + lane; j < end; j += 64) {
        float l = a_src[ssrc[j]] + ad;
        l = (l > 0.f) ? l : NEG_SLOPE * l;
        lbuf[j] = l;
        m = fmaxf(m, l);
    }
    m = wave_reduce_max(m);

    float ssum = 0.f;
    for (int j = beg + lane; j < end; j += 64) {
        float e = __expf(lbuf[j] - m);
        lbuf[j] = e;
        ssum += e;
    }
    ssum = wave_reduce_sum(ssum);
    float inv = 1.f / (ssum + 1e-16f);

    for (int j = beg + lane; j < end; j += 64)
        alpha_out[seid[j]] = lbuf[j] * inv;

    float a0 = 0.f, a1 = 0.f;
    int j = beg;
    for (; j + 3 < end; j += 4) {
        float w0 = lbuf[j] * inv, w1 = lbuf[j + 1] * inv;
        float w2 = lbuf[j + 2] * inv, w3 = lbuf[j + 3] * inv;
        unsigned short q0 = h2b[(size_t)ssrc[j] * D_OUT + lane];
        unsigned short q1 = h2b[(size_t)ssrc[j + 1] * D_OUT + lane];
        unsigned short q2 = h2b[(size_t)ssrc[j + 2] * D_OUT + lane];
        unsigned short q3 = h2b[(size_t)ssrc[j + 3] * D_OUT + lane];
        a0 += w0 * __uint_as_float((unsigned)q0 << 16);
        a1 += w1 * __uint_as_float((unsigned)q1 << 16);
        a0 += w2 * __uint_as_float((unsigned)q2 << 16);
        a1 += w3 * __uint_as_float((unsigned)q3 << 16);
    }
    for (; j < end; j++) {
        float w = lbuf[j] * inv;
        a0 += w * __uint_as_float((unsigned)h2b[(size_t)ssrc[j] * D_OUT + lane] << 16);
    }
    float* orow = out + (size_t)node * D_OUT;
    orow[lane] = a0 + a1 + orow[lane];
}

extern "C" void kernel_launch(void* const* d_in, const int* in_sizes, int n_in,
                              void* d_out, int out_size, void* d_ws, size_t ws_size,
                              hipStream_t stream) {
    const float* x        = (const float*)d_in[0];
    const int*   ei       = (const int*)d_in[1];
    const float* W_src1   = (const float*)d_in[2];
    const float* W_dst1   = (const float*)d_in[3];
    const float* att_src1 = (const float*)d_in[4];
    const float* att_dst1 = (const float*)d_in[5];
    const float* b1       = (const float*)d_in[6];
    const float* W_lin1   = (const float*)d_in[7];
    const float* b_lin1   = (const float*)d_in[8];
    const float* W_src2   = (const float*)d_in[9];
    const float* W_dst2   = (const float*)d_in[10];
    const float* att_src2 = (const float*)d_in[11];
    const float* att_dst2 = (const float*)d_in[12];
    const float* b2       = (const float*)d_in[13];
    const float* W_lin2   = (const float*)d_in[14];
    const float* b_lin2   = (const float*)d_in[15];

    const int Nn = in_sizes[0] / D_IN;   // 50000
    const int E  = in_sizes[1] / 2;      // 800000
    const int* src = ei;
    const int* dst = ei + E;

    char* w = (char*)d_ws;
    auto alloc = [&](size_t bytes) { char* p = w; w += (bytes + 255) & ~(size_t)255; return p; };
    unsigned short* h1b = (unsigned short*)alloc((size_t)Nn * HID * 2);   // bf16 h_src1
    float* lin1   = (float*)alloc((size_t)Nn * HID * 4);                  // x@W_lin1 + b_lin1
    float* h      = (float*)alloc((size_t)Nn * HID * 4);                  // layer-1 output
    unsigned short* h2b = (unsigned short*)alloc((size_t)Nn * D_OUT * 2); // bf16 h_src2
    float* lbuf   = (float*)alloc((size_t)E * 4);
    float* a_src1 = (float*)alloc((size_t)Nn * 4);
    float* a_dst1 = (float*)alloc((size_t)Nn * 4);
    float* a_src2 = (float*)alloc((size_t)Nn * 4);
    float* a_dst2 = (float*)alloc((size_t)Nn * 4);
    int*   deg    = (int*)alloc((size_t)Nn * 4);
    int*   row_ptr= (int*)alloc((size_t)(Nn + 1) * 4);
    int*   cursor = (int*)alloc((size_t)Nn * 4);
    int*   ssrc   = (int*)alloc((size_t)E * 4);
    int*   seid   = (int*)alloc((size_t)E * 4);
    short* Wp1    = (short*)alloc((size_t)16 * 8 * 512 * 2);  // 128 KB
    short* Wp2    = (short*)alloc((size_t)8 * 4 * 512 * 2);   // 32 KB
    float* v_src1 = (float*)alloc(D_IN * 4);
    float* v_dst1 = (float*)alloc(D_IN * 4);
    float* v_src2 = (float*)alloc(HID * 4);
    float* v_dst2 = (float*)alloc(HID * 4);
    float* bsum2  = (float*)alloc(D_OUT * 4);
    int*   bsums  = (int*)alloc(64 * 4);
    int*   boff   = (int*)alloc(64 * 4);

    float* out       = (float*)d_out;
    float* alpha_out = out + (size_t)Nn * D_OUT;

    prep_kernel<<<1, 256, 0, stream>>>(W_src1, att_src1, W_dst1, att_dst1,
                                       W_src2, att_src2, W_dst2, att_dst2,
                                       b2, b_lin2, v_src1, v_dst1, v_src2, v_dst2, bsum2);
    pack_kernel<<<256, 256, 0, stream>>>(W_src1, W_lin1, Wp1, 8, 8, HID);
    pack_kernel<<<64, 256, 0, stream>>>(W_src2, W_lin2, Wp2, 4, 4, D_OUT);

    hipMemsetAsync(deg, 0, (size_t)Nn * 4, stream);
    int eblocks = (E + 255) / 256;
    hist_kernel<<<eblocks, 256, 0, stream>>>(dst, E, deg);
    int nb = (Nn + 1023) / 1024;
    scan_partial<<<nb, 1024, 0, stream>>>(deg, Nn, bsums);
    scan_offsets<<<1, 64, 0, stream>>>(bsums, nb, boff);
    scan_final<<<nb, 1024, 0, stream>>>(deg, Nn, boff, row_ptr, cursor);
    scatter_kernel<<<eblocks, 256, 0, stream>>>(src, dst, E, cursor, ssrc, seid);

    int mtblocks = ((Nn + 15) / 16 + 3) / 4;   // 4 waves (m-tiles) per block
    gemm_fused<8, 8><<<mtblocks, 256, 0, stream>>>(x, Wp1, b_lin1, h1b, lin1, Nn);

    int ablocks = (Nn + 3) / 4;
    akern<<<ablocks, 256, 0, stream>>>(x, v_src1, v_dst1, a_src1, a_dst1, Nn, D_IN);
    agg1_kernel<<<ablocks, 256, 0, stream>>>(row_ptr, ssrc, a_src1, a_dst1, h1b, b1,
                                             lin1, h, lbuf, Nn);

    gemm_fused<4, 4><<<mtblocks, 256, 0, stream>>>(h, Wp2, bsum2, h2b, out, Nn);
    akern<<<ablocks, 256, 0, stream>>>(h, v_src2, v_dst2, a_src2, a_dst2, Nn, HID);
    agg2_kernel<<<ablocks, 256, 0, stream>>>(row_ptr, ssrc, seid, a_src2, a_dst2, h2b,
                                             out, alpha_out, lbuf, Nn);
}

// Round 3
// 401.158 us; speedup vs baseline: 1.6163x; 1.0751x over previous
//
#include <hip/hip_runtime.h>
#include <math.h>

#define D_IN 256
#define HID 128
#define D_OUT 64
#define NEG_SLOPE 0.2f

typedef short short8 __attribute__((ext_vector_type(8)));
typedef float floatx4 __attribute__((ext_vector_type(4)));

__device__ __forceinline__ float wave_reduce_sum(float v) {
    #pragma unroll
    for (int off = 32; off > 0; off >>= 1) v += __shfl_xor(v, off, 64);
    return v;
}
__device__ __forceinline__ float wave_reduce_max(float v) {
    #pragma unroll
    for (int off = 32; off > 0; off >>= 1) v = fmaxf(v, __shfl_xor(v, off, 64));
    return v;
}
__device__ __forceinline__ int wave_reduce_sum_i(int v) {
    #pragma unroll
    for (int off = 32; off > 0; off >>= 1) v += __shfl_xor(v, off, 64);
    return v;
}
__device__ __forceinline__ int wave_scan_incl_i(int v) {
    int lane = threadIdx.x & 63;
    #pragma unroll
    for (int off = 1; off < 64; off <<= 1) {
        int t = __shfl_up(v, off, 64);
        if (lane >= off) v += t;
    }
    return v;
}

__device__ __forceinline__ short f2bf(float f) {           // RNE f32->bf16
    unsigned u = __float_as_uint(f);
    u += 0x7fffu + ((u >> 16) & 1u);
    return (short)(u >> 16);
}
__device__ __forceinline__ float bflo(unsigned p) { return __uint_as_float(p << 16); }
__device__ __forceinline__ float bfhi(unsigned p) { return __uint_as_float(p & 0xffff0000u); }

// ---- prep: v_src/v_dst GEMV weights (W @ att), combined layer-2 bias ----
__global__ void prep_kernel(const float* __restrict__ Wsrc1, const float* __restrict__ att_src1,
                            const float* __restrict__ Wdst1, const float* __restrict__ att_dst1,
                            const float* __restrict__ Wsrc2, const float* __restrict__ att_src2,
                            const float* __restrict__ Wdst2, const float* __restrict__ att_dst2,
                            const float* __restrict__ b2, const float* __restrict__ b_lin2,
                            float* v_src1, float* v_dst1, float* v_src2, float* v_dst2,
                            float* bsum2) {
    int t = threadIdx.x;
    if (t < D_IN) {
        float s1 = 0.f, s2 = 0.f;
        for (int c = 0; c < HID; c++) {
            s1 += Wsrc1[t * HID + c] * att_src1[c];
            s2 += Wdst1[t * HID + c] * att_dst1[c];
        }
        v_src1[t] = s1; v_dst1[t] = s2;
    }
    if (t < HID) {
        float s1 = 0.f, s2 = 0.f;
        for (int c = 0; c < D_OUT; c++) {
            s1 += Wsrc2[t * D_OUT + c] * att_src2[c];
            s2 += Wdst2[t * D_OUT + c] * att_dst2[c];
        }
        v_src2[t] = s1; v_dst2[t] = s2;
    }
    if (t < D_OUT) bsum2[t] = b2[t] + b_lin2[t];
}

// ---- pack [Wa | Wb] into bf16 B-fragment blocks for gemm128 ----
// Wp layout: [y][s][ntl(8)][lane(64)][j(8)] shorts; element = W[k][c] with
// k = s*32 + (lane>>4)*8 + j, c_glob = y*128 + ntl*16 + (lane&15);
// c_glob < NH -> Wa col c_glob, else Wb col c_glob-NH. Total = NY*KS*4096 shorts.
__global__ void pack_kernel(const float* __restrict__ Wa, const float* __restrict__ Wb,
                            short* __restrict__ Wp, int KS, int NH, int total) {
    int idx = blockIdx.x * 256 + threadIdx.x;
    if (idx >= total) return;
    int j = idx & 7;
    int lane = (idx >> 3) & 63;
    int ntl = (idx >> 9) & 7;
    int rest = idx >> 12;
    int s = rest % KS;
    int y = rest / KS;
    int k = s * 32 + ((lane >> 4) * 8) + j;
    int cg = y * 128 + ntl * 16 + (lane & 15);
    const float* W = (cg < NH) ? Wa : Wb;
    int col = (cg < NH) ? cg : cg - NH;
    Wp[idx] = f2bf(W[(size_t)k * NH + col]);
}

// ---- CSR build ----
__global__ void hist_kernel(const int* __restrict__ dst, int E, int* deg) {
    int e = blockIdx.x * 256 + threadIdx.x;
    if (e < E) atomicAdd(&deg[dst[e]], 1);
}

__global__ void scan_partial(const int* __restrict__ deg, int n, int* bsums) {
    __shared__ int ws[16];
    int i = blockIdx.x * 1024 + threadIdx.x;
    int v = (i < n) ? deg[i] : 0;
    int s = wave_reduce_sum_i(v);
    if ((threadIdx.x & 63) == 0) ws[threadIdx.x >> 6] = s;
    __syncthreads();
    if (threadIdx.x == 0) {
        int tot = 0;
        #pragma unroll
        for (int w = 0; w < 16; w++) tot += ws[w];
        bsums[blockIdx.x] = tot;
    }
}

__global__ void scan_offsets(const int* __restrict__ bsums, int nb, int* boff) {
    int lane = threadIdx.x;
    int v = (lane < nb) ? bsums[lane] : 0;
    int incl = wave_scan_incl_i(v);
    if (lane < nb) boff[lane] = incl - v;
}

__global__ void scan_final(const int* __restrict__ deg, int n, const int* __restrict__ boff,
                           int* row_ptr, int* cursor) {
    __shared__ int ws[16];
    int i = blockIdx.x * 1024 + threadIdx.x;
    int wid = threadIdx.x >> 6;
    int v = (i < n) ? deg[i] : 0;
    int sv = wave_scan_incl_i(v);
    if ((threadIdx.x & 63) == 63) ws[wid] = sv;
    __syncthreads();
    if (threadIdx.x == 0) {
        int run = 0;
        #pragma unroll
        for (int w = 0; w < 16; w++) { int t = ws[w]; ws[w] = run; run += t; }
    }
    __syncthreads();
    int excl = boff[blockIdx.x] + ws[wid] + sv - v;
    if (i < n) {
        row_ptr[i] = excl; cursor[i] = excl;
        if (i == n - 1) row_ptr[n] = excl + v;
    }
}

__global__ void scatter_kernel(const int* __restrict__ src, const int* __restrict__ dst, int E,
                               int* cursor, int* ssrc, int* seid) {
    int e = blockIdx.x * 256 + threadIdx.x;
    if (e < E) {
        int d = dst[e];
        int pos = atomicAdd(&cursor[d], 1);
        ssrc[pos] = src[e];
        seid[pos] = e;
    }
}

// ---- canonical 128x128-tile MFMA GEMM: [outb | outf] = A @ [Wa | Wb] ----
// A fp32 [M, K], K = KS*32; staged fp32->bf16 into LDS (80B rows, 2-way free).
// Wp pre-packed bf16 fragments (see pack_kernel). Block = 256 thr = 2x2 waves,
// each wave 64x64 (4x4 tiles of 16x16x32). Logical N = 2*NH; col<NH -> outb
// (bf16, stride NH), else outf (fp32 + bias, stride NH). blockIdx.y = 128-col slab.
template <int KS>
__global__ __launch_bounds__(256) void gemm128(const float* __restrict__ A,
                                               const short* __restrict__ Wp,
                                               const float* __restrict__ bias,
                                               unsigned short* __restrict__ outb,
                                               float* __restrict__ outf,
                                               int M, int NH) {
    const int K = KS * 32;
    __shared__ short A_s[128 * 40];   // 128 rows x 32 bf16, stride 40 shorts (80B)
    __shared__ short B_s[4096];       // one k-step of packed fragments (8KB)

    int tid = threadIdx.x;
    int wave = tid >> 6, lane = tid & 63;
    int wm = wave >> 1, wn = wave & 1;
    int mr = lane & 15, quad = lane >> 4;
    int bm = blockIdx.x * 128;
    int yb = blockIdx.y;

    floatx4 acc[4][4];
    #pragma unroll
    for (int i = 0; i < 4; i++)
        #pragma unroll
        for (int j = 0; j < 4; j++) acc[i][j] = (floatx4){0.f, 0.f, 0.f, 0.f};

    int sr = tid >> 1, shh = tid & 1;            // A staging: row, 16-col half
    int sgrow = bm + sr; if (sgrow >= M) sgrow = M - 1;
    const float* abase = A + (size_t)sgrow * K + shh * 16;
    const short* wbase = Wp + (size_t)yb * KS * 4096 + tid * 16;

    for (int s = 0; s < KS; s++) {
        const float* ap = abase + s * 32;
        float4 f0 = *(const float4*)(ap + 0);
        float4 f1 = *(const float4*)(ap + 4);
        float4 f2 = *(const float4*)(ap + 8);
        float4 f3 = *(const float4*)(ap + 12);
        const short* bp = wbase + (size_t)s * 4096;
        short8 bs0 = *(const short8*)bp;
        short8 bs1 = *(const short8*)(bp + 8);
        short8 alo = {f2bf(f0.x), f2bf(f0.y), f2bf(f0.z), f2bf(f0.w),
                      f2bf(f1.x), f2bf(f1.y), f2bf(f1.z), f2bf(f1.w)};
        short8 ahi = {f2bf(f2.x), f2bf(f2.y), f2bf(f2.z), f2bf(f2.w),
                      f2bf(f3.x), f2bf(f3.y), f2bf(f3.z), f2bf(f3.w)};
        *(short8*)&A_s[sr * 40 + shh * 16 + 0] = alo;
        *(short8*)&A_s[sr * 40 + shh * 16 + 8] = ahi;
        *(short8*)&B_s[tid * 16 + 0] = bs0;
        *(short8*)&B_s[tid * 16 + 8] = bs1;
        __syncthreads();

        short8 af[4], bf[4];
        #pragma unroll
        for (int tm = 0; tm < 4; tm++)
            af[tm] = *(const short8*)&A_s[(wm * 64 + tm * 16 + mr) * 40 + quad * 8];
        #pragma unroll
        for (int tn = 0; tn < 4; tn++)
            bf[tn] = *(const short8*)&B_s[((wn * 4 + tn) * 64 + lane) * 8];
        #pragma unroll
        for (int tm = 0; tm < 4; tm++)
            #pragma unroll
            for (int tn = 0; tn < 4; tn++)
                acc[tm][tn] = __builtin_amdgcn_mfma_f32_16x16x32_bf16(af[tm], bf[tn],
                                                                      acc[tm][tn], 0, 0, 0);
        __syncthreads();
    }

    #pragma unroll
    for (int tm = 0; tm < 4; tm++) {
        #pragma unroll
        for (int tn = 0; tn < 4; tn++) {
            int cg = yb * 128 + wn * 64 + tn * 16 + mr;
            if (cg < NH) {
                #pragma unroll
                for (int r = 0; r < 4; r++) {
                    int grow = bm + wm * 64 + tm * 16 + quad * 4 + r;
                    if (grow < M)
                        outb[(size_t)grow * NH + cg] = (unsigned short)f2bf(acc[tm][tn][r]);
                }
            } else {
                float bv = bias[cg - NH];
                #pragma unroll
                for (int r = 0; r < 4; r++) {
                    int grow = bm + wm * 64 + tm * 16 + quad * 4 + r;
                    if (grow < M)
                        outf[(size_t)grow * NH + (cg - NH)] = acc[tm][tn][r] + bv;
                }
            }
        }
    }
}

// ---- per-node attention scalars ----
__global__ void akern(const float* __restrict__ X, const float* __restrict__ vsrc,
                      const float* __restrict__ vdst, float* a_src, float* a_dst,
                      int Nn, int K) {
    int node = blockIdx.x * 4 + (threadIdx.x >> 6);
    int lane = threadIdx.x & 63;
    if (node >= Nn) return;
    const float* row = X + (size_t)node * K;
    float s1 = 0.f, s2 = 0.f;
    for (int k = lane; k < K; k += 64) {
        float xv = row[k];
        s1 += xv * vsrc[k];
        s2 += xv * vdst[k];
    }
    s1 = wave_reduce_sum(s1);
    s2 = wave_reduce_sum(s2);
    if (lane == 0) { a_src[node] = s1; a_dst[node] = s2; }
}

// ---- layer-1 aggregation: wave per dst node, bf16 gather rows, 4x unroll ----
__global__ void agg1_kernel(const int* __restrict__ row_ptr, const int* __restrict__ ssrc,
                            const float* __restrict__ a_src, const float* __restrict__ a_dst,
                            const unsigned short* __restrict__ h1b, const float* __restrict__ b1,
                            const float* __restrict__ lin, float* __restrict__ hout,
                            float* __restrict__ lbuf, int Nn) {
    int node = blockIdx.x * 4 + (threadIdx.x >> 6);
    int lane = threadIdx.x & 63;
    if (node >= Nn) return;
    int beg = row_ptr[node], end = row_ptr[node + 1];
    float ad = a_dst[node];

    float m = -INFINITY;
    for (int j = beg + lane; j < end; j += 64) {
        float l = a_src[ssrc[j]] + ad;
        l = (l > 0.f) ? l : NEG_SLOPE * l;
        lbuf[j] = l;
        m = fmaxf(m, l);
    }
    m = wave_reduce_max(m);

    float ssum = 0.f;
    for (int j = beg + lane; j < end; j += 64) {
        float e = __expf(lbuf[j] - m);
        lbuf[j] = e;
        ssum += e;
    }
    ssum = wave_reduce_sum(ssum);
    float inv = 1.f / (ssum + 1e-16f);

    float ax0 = 0.f, ay0 = 0.f, ax1 = 0.f, ay1 = 0.f;
    int j = beg;
    for (; j + 3 < end; j += 4) {
        float w0 = lbuf[j] * inv, w1 = lbuf[j + 1] * inv;
        float w2 = lbuf[j + 2] * inv, w3 = lbuf[j + 3] * inv;
        int s0 = ssrc[j], s1 = ssrc[j + 1], s2 = ssrc[j + 2], s3 = ssrc[j + 3];
        unsigned p0 = *(const unsigned*)(h1b + (size_t)s0 * HID + lane * 2);
        unsigned p1 = *(const unsigned*)(h1b + (size_t)s1 * HID + lane * 2);
        unsigned p2 = *(const unsigned*)(h1b + (size_t)s2 * HID + lane * 2);
        unsigned p3 = *(const unsigned*)(h1b + (size_t)s3 * HID + lane * 2);
        ax0 += w0 * bflo(p0); ay0 += w0 * bfhi(p0);
        ax1 += w1 * bflo(p1); ay1 += w1 * bfhi(p1);
        ax0 += w2 * bflo(p2); ay0 += w2 * bfhi(p2);
        ax1 += w3 * bflo(p3); ay1 += w3 * bfhi(p3);
    }
    for (; j < end; j++) {
        float w = lbuf[j] * inv;
        unsigned p = *(const unsigned*)(h1b + (size_t)ssrc[j] * HID + lane * 2);
        ax0 += w * bflo(p); ay0 += w * bfhi(p);
    }
    int c = lane * 2;
    const float* lrow = lin + (size_t)node * HID;
    float* orow = hout + (size_t)node * HID;
    orow[c + 0] = fmaxf(ax0 + ax1 + b1[c + 0] + lrow[c + 0], 0.f);
    orow[c + 1] = fmaxf(ay0 + ay1 + b1[c + 1] + lrow[c + 1], 0.f);
}

// ---- layer-2 aggregation (+ alpha output), bf16 gather rows ----
__global__ void agg2_kernel(const int* __restrict__ row_ptr, const int* __restrict__ ssrc,
                            const int* __restrict__ seid,
                            const float* __restrict__ a_src, const float* __restrict__ a_dst,
                            const unsigned short* __restrict__ h2b,
                            float* __restrict__ out, float* __restrict__ alpha_out,
                            float* __restrict__ lbuf, int Nn) {
    int node = blockIdx.x * 4 + (threadIdx.x >> 6);
    int lane = threadIdx.x & 63;
    if (node >= Nn) return;
    int beg = row_ptr[node], end = row_ptr[node + 1];
    float ad = a_dst[node];

    float m = -INFINITY;
    for (int j = beg + lane; j < end; j += 64) {
        float l = a_src[ssrc[j]] + ad;
        l = (l > 0.f) ? l : NEG_SLOPE * l;
        lbuf[j] = l;
        m = fmaxf(m, l);
    }
    m = wave_reduce_max(m);

    float ssum = 0.f;
    for (int j = beg + lane; j < end; j += 64) {
        float e = __expf(lbuf[j] - m);
        lbuf[j] = e;
        ssum += e;
    }
    ssum = wave_reduce_sum(ssum);
    float inv = 1.f / (ssum + 1e-16f);

    for (int j = beg + lane; j < end; j += 64)
        alpha_out[seid[j]] = lbuf[j] * inv;

    float a0 = 0.f, a1 = 0.f;
    int j = beg;
    for (; j + 3 < end; j += 4) {
        float w0 = lbuf[j] * inv, w1 = lbuf[j + 1] * inv;
        float w2 = lbuf[j + 2] * inv, w3 = lbuf[j + 3] * inv;
        unsigned short q0 = h2b[(size_t)ssrc[j] * D_OUT + lane];
        unsigned short q1 = h2b[(size_t)ssrc[j + 1] * D_OUT + lane];
        unsigned short q2 = h2b[(size_t)ssrc[j + 2] * D_OUT + lane];
        unsigned short q3 = h2b[(size_t)ssrc[j + 3] * D_OUT + lane];
        a0 += w0 * __uint_as_float((unsigned)q0 << 16);
        a1 += w1 * __uint_as_float((unsigned)q1 << 16);
        a0 += w2 * __uint_as_float((unsigned)q2 << 16);
        a1 += w3 * __uint_as_float((unsigned)q3 << 16);
    }
    for (; j < end; j++) {
        float w = lbuf[j] * inv;
        a0 += w * __uint_as_float((unsigned)h2b[(size_t)ssrc[j] * D_OUT + lane] << 16);
    }
    float* orow = out + (size_t)node * D_OUT;
    orow[lane] = a0 + a1 + orow[lane];
}

extern "C" void kernel_launch(void* const* d_in, const int* in_sizes, int n_in,
                              void* d_out, int out_size, void* d_ws, size_t ws_size,
                              hipStream_t stream) {
    const float* x        = (const float*)d_in[0];
    const int*   ei       = (const int*)d_in[1];
    const float* W_src1   = (const float*)d_in[2];
    const float* W_dst1   = (const float*)d_in[3];
    const float* att_src1 = (const float*)d_in[4];
    const float* att_dst1 = (const float*)d_in[5];
    const float* b1       = (const float*)d_in[6];
    const float* W_lin1   = (const float*)d_in[7];
    const float* b_lin1   = (const float*)d_in[8];
    const float* W_src2   = (const float*)d_in[9];
    const float* W_dst2   = (const float*)d_in[10];
    const float* att_src2 = (const float*)d_in[11];
    const float* att_dst2 = (const float*)d_in[12];
    const float* b2       = (const float*)d_in[13];
    const float* W_lin2   = (const float*)d_in[14];
    const float* b_lin2   = (const float*)d_in[15];

    const int Nn = in_sizes[0] / D_IN;   // 50000
    const int E  = in_sizes[1] / 2;      // 800000
    const int* src = ei;
    const int* dst = ei + E;

    char* w = (char*)d_ws;
    auto alloc = [&](size_t bytes) { char* p = w; w += (bytes + 255) & ~(size_t)255; return p; };
    unsigned short* h1b = (unsigned short*)alloc((size_t)Nn * HID * 2);   // bf16 h_src1
    float* lin1   = (float*)alloc((size_t)Nn * HID * 4);                  // x@W_lin1 + b_lin1
    float* h      = (float*)alloc((size_t)Nn * HID * 4);                  // layer-1 output
    unsigned short* h2b = (unsigned short*)alloc((size_t)Nn * D_OUT * 2); // bf16 h_src2
    float* lbuf   = (float*)alloc((size_t)E * 4);
    float* a_src1 = (float*)alloc((size_t)Nn * 4);
    float* a_dst1 = (float*)alloc((size_t)Nn * 4);
    float* a_src2 = (float*)alloc((size_t)Nn * 4);
    float* a_dst2 = (float*)alloc((size_t)Nn * 4);
    int*   deg    = (int*)alloc((size_t)Nn * 4);
    int*   row_ptr= (int*)alloc((size_t)(Nn + 1) * 4);
    int*   cursor = (int*)alloc((size_t)Nn * 4);
    int*   ssrc   = (int*)alloc((size_t)E * 4);
    int*   seid   = (int*)alloc((size_t)E * 4);
    short* Wp1    = (short*)alloc((size_t)2 * 8 * 4096 * 2);  // 128 KB
    short* Wp2    = (short*)alloc((size_t)1 * 4 * 4096 * 2);  // 32 KB
    float* v_src1 = (float*)alloc(D_IN * 4);
    float* v_dst1 = (float*)alloc(D_IN * 4);
    float* v_src2 = (float*)alloc(HID * 4);
    float* v_dst2 = (float*)alloc(HID * 4);
    float* bsum2  = (float*)alloc(D_OUT * 4);
    int*   bsums  = (int*)alloc(64 * 4);
    int*   boff   = (int*)alloc(64 * 4);

    float* out       = (float*)d_out;
    float* alpha_out = out + (size_t)Nn * D_OUT;

    prep_kernel<<<1, 256, 0, stream>>>(W_src1, att_src1, W_dst1, att_dst1,
                                       W_src2, att_src2, W_dst2, att_dst2,
                                       b2, b_lin2, v_src1, v_dst1, v_src2, v_dst2, bsum2);
    pack_kernel<<<256, 256, 0, stream>>>(W_src1, W_lin1, Wp1, 8, HID, 2 * 8 * 4096);
    pack_kernel<<<64, 256, 0, stream>>>(W_src2, W_lin2, Wp2, 4, D_OUT, 1 * 4 * 4096);

    hipMemsetAsync(deg, 0, (size_t)Nn * 4, stream);
    int eblocks = (E + 255) / 256;
    hist_kernel<<<eblocks, 256, 0, stream>>>(dst, E, deg);
    int nb = (Nn + 1023) / 1024;
    scan_partial<<<nb, 1024, 0, stream>>>(deg, Nn, bsums);
    scan_offsets<<<1, 64, 0, stream>>>(bsums, nb, boff);
    scan_final<<<nb, 1024, 0, stream>>>(deg, Nn, boff, row_ptr, cursor);
    scatter_kernel<<<eblocks, 256, 0, stream>>>(src, dst, E, cursor, ssrc, seid);

    int mblocks = (Nn + 127) / 128;   // 391
    gemm128<8><<<dim3(mblocks, 2), 256, 0, stream>>>(x, Wp1, b_lin1, h1b, lin1, Nn, HID);

    int ablocks = (Nn + 3) / 4;
    akern<<<ablocks, 256, 0, stream>>>(x, v_src1, v_dst1, a_src1, a_dst1, Nn, D_IN);
    agg1_kernel<<<ablocks, 256, 0, stream>>>(row_ptr, ssrc, a_src1, a_dst1, h1b, b1,
                                             lin1, h, lbuf, Nn);

    gemm128<4><<<dim3(mblocks, 1), 256, 0, stream>>>(h, Wp2, bsum2, h2b, out, Nn, D_OUT);
    akern<<<ablocks, 256, 0, stream>>>(h, v_src2, v_dst2, a_src2, a_dst2, Nn, HID);
    agg2_kernel<<<ablocks, 256, 0, stream>>>(row_ptr, ssrc, seid, a_src2, a_dst2, h2b,
                                             out, alpha_out, lbuf, Nn);
}

// Round 4
// 401.034 us; speedup vs baseline: 1.6168x; 1.0003x over previous
//
#include <hip/hip_runtime.h>
#include <math.h>

#define D_IN 256
#define HID 128
#define D_OUT 64
#define NEG_SLOPE 0.2f

typedef short short8 __attribute__((ext_vector_type(8)));
typedef float floatx4 __attribute__((ext_vector_type(4)));

__device__ __forceinline__ float wave_reduce_sum(float v) {
    #pragma unroll
    for (int off = 32; off > 0; off >>= 1) v += __shfl_xor(v, off, 64);
    return v;
}
__device__ __forceinline__ float wave_reduce_max(float v) {
    #pragma unroll
    for (int off = 32; off > 0; off >>= 1) v = fmaxf(v, __shfl_xor(v, off, 64));
    return v;
}
__device__ __forceinline__ int wave_reduce_sum_i(int v) {
    #pragma unroll
    for (int off = 32; off > 0; off >>= 1) v += __shfl_xor(v, off, 64);
    return v;
}
__device__ __forceinline__ int wave_scan_incl_i(int v) {
    int lane = threadIdx.x & 63;
    #pragma unroll
    for (int off = 1; off < 64; off <<= 1) {
        int t = __shfl_up(v, off, 64);
        if (lane >= off) v += t;
    }
    return v;
}

__device__ __forceinline__ short f2bf(float f) {           // RNE f32->bf16
    unsigned u = __float_as_uint(f);
    u += 0x7fffu + ((u >> 16) & 1u);
    return (short)(u >> 16);
}
__device__ __forceinline__ float bflo(unsigned p) { return __uint_as_float(p << 16); }
__device__ __forceinline__ float bfhi(unsigned p) { return __uint_as_float(p & 0xffff0000u); }

// ---- prep: v_src/v_dst GEMV weights (W @ att), combined layer-2 bias ----
__global__ void prep_kernel(const float* __restrict__ Wsrc1, const float* __restrict__ att_src1,
                            const float* __restrict__ Wdst1, const float* __restrict__ att_dst1,
                            const float* __restrict__ Wsrc2, const float* __restrict__ att_src2,
                            const float* __restrict__ Wdst2, const float* __restrict__ att_dst2,
                            const float* __restrict__ b2, const float* __restrict__ b_lin2,
                            float* v_src1, float* v_dst1, float* v_src2, float* v_dst2,
                            float* bsum2) {
    int t = threadIdx.x;
    if (t < D_IN) {
        float s1 = 0.f, s2 = 0.f;
        for (int c = 0; c < HID; c++) {
            s1 += Wsrc1[t * HID + c] * att_src1[c];
            s2 += Wdst1[t * HID + c] * att_dst1[c];
        }
        v_src1[t] = s1; v_dst1[t] = s2;
    }
    if (t < HID) {
        float s1 = 0.f, s2 = 0.f;
        for (int c = 0; c < D_OUT; c++) {
            s1 += Wsrc2[t * D_OUT + c] * att_src2[c];
            s2 += Wdst2[t * D_OUT + c] * att_dst2[c];
        }
        v_src2[t] = s1; v_dst2[t] = s2;
    }
    if (t < D_OUT) bsum2[t] = b2[t] + b_lin2[t];
}

// ---- pack [Wa | Wb] into bf16 B-fragment stream for gemm_k ----
// Wp[((s*NTG + nt)*64 + lane)*8 + j] = W[k][col], k = s*32 + (lane>>4)*8 + j,
// cg = nt*16 + (lane&15); cg < NH -> Wa col cg, else Wb col cg-NH.
__global__ void pack_kernel(const float* __restrict__ Wa, const float* __restrict__ Wb,
                            short* __restrict__ Wp, int NTG, int NH, int total) {
    int idx = blockIdx.x * 256 + threadIdx.x;
    if (idx >= total) return;
    int j = idx & 7;
    int lane = (idx >> 3) & 63;
    int r = idx >> 9;
    int nt = r % NTG;
    int s = r / NTG;
    int k = s * 32 + ((lane >> 4) * 8) + j;
    int cg = nt * 16 + (lane & 15);
    const float* W = (cg < NH) ? Wa : Wb;
    int col = (cg < NH) ? cg : cg - NH;
    Wp[idx] = f2bf(W[(size_t)k * NH + col]);
}

// ---- CSR build ----
__global__ void hist_kernel(const int* __restrict__ dst, int E, int* deg) {
    int e = blockIdx.x * 256 + threadIdx.x;
    if (e < E) atomicAdd(&deg[dst[e]], 1);
}

__global__ void scan_partial(const int* __restrict__ deg, int n, int* bsums) {
    __shared__ int ws[16];
    int i = blockIdx.x * 1024 + threadIdx.x;
    int v = (i < n) ? deg[i] : 0;
    int s = wave_reduce_sum_i(v);
    if ((threadIdx.x & 63) == 0) ws[threadIdx.x >> 6] = s;
    __syncthreads();
    if (threadIdx.x == 0) {
        int tot = 0;
        #pragma unroll
        for (int w = 0; w < 16; w++) tot += ws[w];
        bsums[blockIdx.x] = tot;
    }
}

__global__ void scan_offsets(const int* __restrict__ bsums, int nb, int* boff) {
    int lane = threadIdx.x;
    int v = (lane < nb) ? bsums[lane] : 0;
    int incl = wave_scan_incl_i(v);
    if (lane < nb) boff[lane] = incl - v;
}

__global__ void scan_final(const int* __restrict__ deg, int n, const int* __restrict__ boff,
                           int* row_ptr, int* cursor) {
    __shared__ int ws[16];
    int i = blockIdx.x * 1024 + threadIdx.x;
    int wid = threadIdx.x >> 6;
    int v = (i < n) ? deg[i] : 0;
    int sv = wave_scan_incl_i(v);
    if ((threadIdx.x & 63) == 63) ws[wid] = sv;
    __syncthreads();
    if (threadIdx.x == 0) {
        int run = 0;
        #pragma unroll
        for (int w = 0; w < 16; w++) { int t = ws[w]; ws[w] = run; run += t; }
    }
    __syncthreads();
    int excl = boff[blockIdx.x] + ws[wid] + sv - v;
    if (i < n) {
        row_ptr[i] = excl; cursor[i] = excl;
        if (i == n - 1) row_ptr[n] = excl + v;
    }
}

__global__ void scatter_kernel(const int* __restrict__ src, const int* __restrict__ dst, int E,
                               int* cursor, int* ssrc) {
    int e = blockIdx.x * 256 + threadIdx.x;
    if (e < E) {
        int d = dst[e];
        int pos = atomicAdd(&cursor[d], 1);
        ssrc[pos] = src[e];
    }
}

// ---- canonical MFMA GEMM, single column slab: [outb | outf] = A @ [Wa | Wb] ----
// Block tile 128 x (2*NT*16); 4 waves as 2x2, wave tile 64 x (NT*16).
// AF32: A fp32, converted in staging (optionally fusing a_src/a_dst fp32 dots);
// else A bf16 (direct copy). NH = NT*16; col<NH -> outb bf16, else outf fp32+bias.
template <int KS, int NT, bool AF32, bool ATT>
__global__ __launch_bounds__(256) void gemm_k(const void* __restrict__ Av,
                                              const short* __restrict__ Wp,
                                              const float* __restrict__ bias,
                                              const float* __restrict__ vsrc,
                                              const float* __restrict__ vdst,
                                              float* __restrict__ a_src,
                                              float* __restrict__ a_dst,
                                              unsigned short* __restrict__ outb,
                                              float* __restrict__ outf, int M) {
    const int K = KS * 32;
    const int NH = NT * 16;
    const int BS = NT * 2 * 512;              // B_s shorts per k-step
    __shared__ short A_s[128 * 40];           // 128 rows x 32 bf16, stride 40
    __shared__ short B_s[BS];

    int tid = threadIdx.x;
    int wave = tid >> 6, lane = tid & 63;
    int wm = wave >> 1, wn = wave & 1;
    int mr = lane & 15, quad = lane >> 4;
    int bm = blockIdx.x * 128;

    floatx4 acc[4][NT];
    #pragma unroll
    for (int i = 0; i < 4; i++)
        #pragma unroll
        for (int j = 0; j < NT; j++) acc[i][j] = (floatx4){0.f, 0.f, 0.f, 0.f};

    int sr = tid >> 1, shh = tid & 1;         // A staging: row, 16-elem half
    int grow = bm + sr;
    int crow = (grow < M) ? grow : M - 1;
    float psrc = 0.f, pdst = 0.f;

    for (int s = 0; s < KS; s++) {
        if (AF32) {
            const float* ap = (const float*)Av + (size_t)crow * K + s * 32 + shh * 16;
            float4 f0 = *(const float4*)(ap + 0);
            float4 f1 = *(const float4*)(ap + 4);
            float4 f2 = *(const float4*)(ap + 8);
            float4 f3 = *(const float4*)(ap + 12);
            if (ATT) {
                const float* vs = vsrc + s * 32 + shh * 16;
                const float* vd = vdst + s * 32 + shh * 16;
                float fa[16] = {f0.x, f0.y, f0.z, f0.w, f1.x, f1.y, f1.z, f1.w,
                                f2.x, f2.y, f2.z, f2.w, f3.x, f3.y, f3.z, f3.w};
                #pragma unroll
                for (int i = 0; i < 16; i++) {
                    psrc += fa[i] * vs[i];
                    pdst += fa[i] * vd[i];
                }
            }
            short8 alo = {f2bf(f0.x), f2bf(f0.y), f2bf(f0.z), f2bf(f0.w),
                          f2bf(f1.x), f2bf(f1.y), f2bf(f1.z), f2bf(f1.w)};
            short8 ahi = {f2bf(f2.x), f2bf(f2.y), f2bf(f2.z), f2bf(f2.w),
                          f2bf(f3.x), f2bf(f3.y), f2bf(f3.z), f2bf(f3.w)};
            *(short8*)&A_s[sr * 40 + shh * 16 + 0] = alo;
            *(short8*)&A_s[sr * 40 + shh * 16 + 8] = ahi;
        } else {
            const unsigned short* ap = (const unsigned short*)Av + (size_t)crow * K + s * 32 + shh * 16;
            short8 alo = *(const short8*)(ap + 0);
            short8 ahi = *(const short8*)(ap + 8);
            *(short8*)&A_s[sr * 40 + shh * 16 + 0] = alo;
            *(short8*)&A_s[sr * 40 + shh * 16 + 8] = ahi;
        }
        {   // B staging: linear copy, BS/256 shorts per thread
            const short* bp = Wp + (size_t)s * BS + tid * (BS / 256);
            short* bq = &B_s[tid * (BS / 256)];
            #pragma unroll
            for (int c = 0; c < BS / 256 / 8; c++)
                *(short8*)(bq + c * 8) = *(const short8*)(bp + c * 8);
        }
        __syncthreads();

        short8 af[4];
        #pragma unroll
        for (int tm = 0; tm < 4; tm++)
            af[tm] = *(const short8*)&A_s[(wm * 64 + tm * 16 + mr) * 40 + quad * 8];
        #pragma unroll
        for (int tn = 0; tn < NT; tn++) {
            short8 bfr = *(const short8*)&B_s[((wn * NT + tn) * 64 + lane) * 8];
            #pragma unroll
            for (int tm = 0; tm < 4; tm++)
                acc[tm][tn] = __builtin_amdgcn_mfma_f32_16x16x32_bf16(af[tm], bfr,
                                                                      acc[tm][tn], 0, 0, 0);
        }
        __syncthreads();
    }

    if (ATT) {
        psrc += __shfl_xor(psrc, 1, 64);
        pdst += __shfl_xor(pdst, 1, 64);
        if (shh == 0 && grow < M) { a_src[grow] = psrc; a_dst[grow] = pdst; }
    }

    #pragma unroll
    for (int tm = 0; tm < 4; tm++) {
        #pragma unroll
        for (int tn = 0; tn < NT; tn++) {
            int cg = wn * NH + tn * 16 + mr;   // logical col in [0, 2*NH)
            if (cg < NH) {
                #pragma unroll
                for (int r = 0; r < 4; r++) {
                    int gr = bm + wm * 64 + tm * 16 + quad * 4 + r;
                    if (gr < M)
                        outb[(size_t)gr * NH + cg] = (unsigned short)f2bf(acc[tm][tn][r]);
                }
            } else {
                float bv = bias[cg - NH];
                #pragma unroll
                for (int r = 0; r < 4; r++) {
                    int gr = bm + wm * 64 + tm * 16 + quad * 4 + r;
                    if (gr < M)
                        outf[(size_t)gr * NH + (cg - NH)] = acc[tm][tn][r] + bv;
                }
            }
        }
    }
}

// ---- layer-1 aggregation: wave per dst node; writes h bf16 + layer-2 att scalars ----
__global__ void agg1_kernel(const int* __restrict__ row_ptr, const int* __restrict__ ssrc,
                            const float* __restrict__ a_src, const float* __restrict__ a_dst,
                            const unsigned short* __restrict__ h1b, const float* __restrict__ b1,
                            const float* __restrict__ lin,
                            const float* __restrict__ vs2, const float* __restrict__ vd2,
                            unsigned short* __restrict__ hb,
                            float* __restrict__ a_src2, float* __restrict__ a_dst2,
                            float* __restrict__ lbuf, int Nn) {
    int node = blockIdx.x * 4 + (threadIdx.x >> 6);
    int lane = threadIdx.x & 63;
    if (node >= Nn) return;
    int beg = row_ptr[node], end = row_ptr[node + 1];
    float ad = a_dst[node];

    float m = -INFINITY;
    for (int j = beg + lane; j < end; j += 64) {
        float l = a_src[ssrc[j]] + ad;
        l = (l > 0.f) ? l : NEG_SLOPE * l;
        lbuf[j] = l;
        m = fmaxf(m, l);
    }
    m = wave_reduce_max(m);

    float ssum = 0.f;
    for (int j = beg + lane; j < end; j += 64) {
        float e = __expf(lbuf[j] - m);
        lbuf[j] = e;
        ssum += e;
    }
    ssum = wave_reduce_sum(ssum);
    float inv = 1.f / (ssum + 1e-16f);

    float ax0 = 0.f, ay0 = 0.f, ax1 = 0.f, ay1 = 0.f;
    int j = beg;
    for (; j + 3 < end; j += 4) {
        float w0 = lbuf[j] * inv, w1 = lbuf[j + 1] * inv;
        float w2 = lbuf[j + 2] * inv, w3 = lbuf[j + 3] * inv;
        int s0 = ssrc[j], s1 = ssrc[j + 1], s2 = ssrc[j + 2], s3 = ssrc[j + 3];
        unsigned p0 = *(const unsigned*)(h1b + (size_t)s0 * HID + lane * 2);
        unsigned p1 = *(const unsigned*)(h1b + (size_t)s1 * HID + lane * 2);
        unsigned p2 = *(const unsigned*)(h1b + (size_t)s2 * HID + lane * 2);
        unsigned p3 = *(const unsigned*)(h1b + (size_t)s3 * HID + lane * 2);
        ax0 += w0 * bflo(p0); ay0 += w0 * bfhi(p0);
        ax1 += w1 * bflo(p1); ay1 += w1 * bfhi(p1);
        ax0 += w2 * bflo(p2); ay0 += w2 * bfhi(p2);
        ax1 += w3 * bflo(p3); ay1 += w3 * bfhi(p3);
    }
    for (; j < end; j++) {
        float w = lbuf[j] * inv;
        unsigned p = *(const unsigned*)(h1b + (size_t)ssrc[j] * HID + lane * 2);
        ax0 += w * bflo(p); ay0 += w * bfhi(p);
    }
    int c = lane * 2;
    const float* lrow = lin + (size_t)node * HID;
    float ox = fmaxf(ax0 + ax1 + b1[c + 0] + lrow[c + 0], 0.f);
    float oy = fmaxf(ay0 + ay1 + b1[c + 1] + lrow[c + 1], 0.f);
    unsigned pk = (unsigned)(unsigned short)f2bf(ox) | ((unsigned)(unsigned short)f2bf(oy) << 16);
    *(unsigned*)&hb[(size_t)node * HID + c] = pk;

    // layer-2 attention scalars from exact fp32 h
    float ps = ox * vs2[c] + oy * vs2[c + 1];
    float pd = ox * vd2[c] + oy * vd2[c + 1];
    ps = wave_reduce_sum(ps);
    pd = wave_reduce_sum(pd);
    if (lane == 0) { a_src2[node] = ps; a_dst2[node] = pd; }
}

// ---- layer-2 aggregation; saves (m, inv) per node for the alpha pass ----
__global__ void agg2_kernel(const int* __restrict__ row_ptr, const int* __restrict__ ssrc,
                            const float* __restrict__ a_src, const float* __restrict__ a_dst,
                            const unsigned short* __restrict__ h2b,
                            float* __restrict__ out, float2* __restrict__ sm2,
                            float* __restrict__ lbuf, int Nn) {
    int node = blockIdx.x * 4 + (threadIdx.x >> 6);
    int lane = threadIdx.x & 63;
    if (node >= Nn) return;
    int beg = row_ptr[node], end = row_ptr[node + 1];
    float ad = a_dst[node];

    float m = -INFINITY;
    for (int j = beg + lane; j < end; j += 64) {
        float l = a_src[ssrc[j]] + ad;
        l = (l > 0.f) ? l : NEG_SLOPE * l;
        lbuf[j] = l;
        m = fmaxf(m, l);
    }
    m = wave_reduce_max(m);

    float ssum = 0.f;
    for (int j = beg + lane; j < end; j += 64) {
        float e = __expf(lbuf[j] - m);
        lbuf[j] = e;
        ssum += e;
    }
    ssum = wave_reduce_sum(ssum);
    float inv = 1.f / (ssum + 1e-16f);
    if (lane == 0) sm2[node] = make_float2(m, inv);

    float a0 = 0.f, a1 = 0.f;
    int j = beg;
    for (; j + 3 < end; j += 4) {
        float w0 = lbuf[j] * inv, w1 = lbuf[j + 1] * inv;
        float w2 = lbuf[j + 2] * inv, w3 = lbuf[j + 3] * inv;
        unsigned short q0 = h2b[(size_t)ssrc[j] * D_OUT + lane];
        unsigned short q1 = h2b[(size_t)ssrc[j + 1] * D_OUT + lane];
        unsigned short q2 = h2b[(size_t)ssrc[j + 2] * D_OUT + lane];
        unsigned short q3 = h2b[(size_t)ssrc[j + 3] * D_OUT + lane];
        a0 += w0 * __uint_as_float((unsigned)q0 << 16);
        a1 += w1 * __uint_as_float((unsigned)q1 << 16);
        a0 += w2 * __uint_as_float((unsigned)q2 << 16);
        a1 += w3 * __uint_as_float((unsigned)q3 << 16);
    }
    for (; j < end; j++) {
        float w = lbuf[j] * inv;
        a0 += w * __uint_as_float((unsigned)h2b[(size_t)ssrc[j] * D_OUT + lane] << 16);
    }
    float* orow = out + (size_t)node * D_OUT;
    orow[lane] = a0 + a1 + orow[lane];
}

// ---- alpha in original edge order: coalesced reads/writes, L2-resident tables ----
__global__ void alpha_kernel(const int* __restrict__ src, const int* __restrict__ dst,
                             const float* __restrict__ a_src2, const float* __restrict__ a_dst2,
                             const float2* __restrict__ sm2, float* __restrict__ alpha, int E) {
    int e = blockIdx.x * 256 + threadIdx.x;
    if (e >= E) return;
    int s = src[e], d = dst[e];
    float l = a_src2[s] + a_dst2[d];
    l = (l > 0.f) ? l : NEG_SLOPE * l;
    float2 mi = sm2[d];
    alpha[e] = __expf(l - mi.x) * mi.y;
}

extern "C" void kernel_launch(void* const* d_in, const int* in_sizes, int n_in,
                              void* d_out, int out_size, void* d_ws, size_t ws_size,
                              hipStream_t stream) {
    const float* x        = (const float*)d_in[0];
    const int*   ei       = (const int*)d_in[1];
    const float* W_src1   = (const float*)d_in[2];
    const float* W_dst1   = (const float*)d_in[3];
    const float* att_src1 = (const float*)d_in[4];
    const float* att_dst1 = (const float*)d_in[5];
    const float* b1       = (const float*)d_in[6];
    const float* W_lin1   = (const float*)d_in[7];
    const float* b_lin1   = (const float*)d_in[8];
    const float* W_src2   = (const float*)d_in[9];
    const float* W_dst2   = (const float*)d_in[10];
    const float* att_src2 = (const float*)d_in[11];
    const float* att_dst2 = (const float*)d_in[12];
    const float* b2       = (const float*)d_in[13];
    const float* W_lin2   = (const float*)d_in[14];
    const float* b_lin2   = (const float*)d_in[15];

    const int Nn = in_sizes[0] / D_IN;   // 50000
    const int E  = in_sizes[1] / 2;      // 800000
    const int* src = ei;
    const int* dst = ei + E;

    char* w = (char*)d_ws;
    auto alloc = [&](size_t bytes) { char* p = w; w += (bytes + 255) & ~(size_t)255; return p; };
    unsigned short* h1b = (unsigned short*)alloc((size_t)Nn * HID * 2);   // bf16 h_src1
    float* lin1   = (float*)alloc((size_t)Nn * HID * 4);                  // x@W_lin1 + b_lin1
    unsigned short* hb  = (unsigned short*)alloc((size_t)Nn * HID * 2);   // bf16 h (layer-1 out)
    unsigned short* h2b = (unsigned short*)alloc((size_t)Nn * D_OUT * 2); // bf16 h_src2
    float* lbuf   = (float*)alloc((size_t)E * 4);
    float* a_src1 = (float*)alloc((size_t)Nn * 4);
    float* a_dst1 = (float*)alloc((size_t)Nn * 4);
    float* a_src2 = (float*)alloc((size_t)Nn * 4);
    float* a_dst2 = (float*)alloc((size_t)Nn * 4);
    float2* sm2   = (float2*)alloc((size_t)Nn * 8);
    int*   deg    = (int*)alloc((size_t)Nn * 4);
    int*   row_ptr= (int*)alloc((size_t)(Nn + 1) * 4);
    int*   cursor = (int*)alloc((size_t)Nn * 4);
    int*   ssrc   = (int*)alloc((size_t)E * 4);
    short* Wp1    = (short*)alloc((size_t)8 * 16 * 512 * 2);  // 128 KB
    short* Wp2    = (short*)alloc((size_t)4 * 8 * 512 * 2);   // 32 KB
    float* v_src1 = (float*)alloc(D_IN * 4);
    float* v_dst1 = (float*)alloc(D_IN * 4);
    float* v_src2 = (float*)alloc(HID * 4);
    float* v_dst2 = (float*)alloc(HID * 4);
    float* bsum2  = (float*)alloc(D_OUT * 4);
    int*   bsums  = (int*)alloc(64 * 4);
    int*   boff   = (int*)alloc(64 * 4);

    float* out       = (float*)d_out;
    float* alpha_out = out + (size_t)Nn * D_OUT;

    prep_kernel<<<1, 256, 0, stream>>>(W_src1, att_src1, W_dst1, att_dst1,
                                       W_src2, att_src2, W_dst2, att_dst2,
                                       b2, b_lin2, v_src1, v_dst1, v_src2, v_dst2, bsum2);
    pack_kernel<<<256, 256, 0, stream>>>(W_src1, W_lin1, Wp1, 16, HID, 8 * 16 * 512);
    pack_kernel<<<64, 256, 0, stream>>>(W_src2, W_lin2, Wp2, 8, D_OUT, 4 * 8 * 512);

    hipMemsetAsync(deg, 0, (size_t)Nn * 4, stream);
    int eblocks = (E + 255) / 256;
    hist_kernel<<<eblocks, 256, 0, stream>>>(dst, E, deg);
    int nb = (Nn + 1023) / 1024;
    scan_partial<<<nb, 1024, 0, stream>>>(deg, Nn, bsums);
    scan_offsets<<<1, 64, 0, stream>>>(bsums, nb, boff);
    scan_final<<<nb, 1024, 0, stream>>>(deg, Nn, boff, row_ptr, cursor);
    scatter_kernel<<<eblocks, 256, 0, stream>>>(src, dst, E, cursor, ssrc);

    int mblocks = (Nn + 127) / 128;   // 391
    gemm_k<8, 8, true, true><<<mblocks, 256, 0, stream>>>(x, Wp1, b_lin1, v_src1, v_dst1,
                                                          a_src1, a_dst1, h1b, lin1, Nn);

    int ablocks = (Nn + 3) / 4;
    agg1_kernel<<<ablocks, 256, 0, stream>>>(row_ptr, ssrc, a_src1, a_dst1, h1b, b1, lin1,
                                             v_src2, v_dst2, hb, a_src2, a_dst2, lbuf, Nn);

    gemm_k<4, 4, false, false><<<mblocks, 256, 0, stream>>>(hb, Wp2, bsum2, nullptr, nullptr,
                                                            nullptr, nullptr, h2b, out, Nn);
    agg2_kernel<<<ablocks, 256, 0, stream>>>(row_ptr, ssrc, a_src2, a_dst2, h2b,
                                             out, sm2, lbuf, Nn);
    alpha_kernel<<<eblocks, 256, 0, stream>>>(src, dst, a_src2, a_dst2, sm2, alpha_out, E);
}

// Round 5
// 377.391 us; speedup vs baseline: 1.7181x; 1.0626x over previous
//
#include <hip/hip_runtime.h>
#include <math.h>

#define D_IN 256
#define HID 128
#define D_OUT 64
#define NEG_SLOPE 0.2f

typedef short short8 __attribute__((ext_vector_type(8)));
typedef float floatx4 __attribute__((ext_vector_type(4)));

__device__ __forceinline__ float wave_reduce_sum(float v) {
    #pragma unroll
    for (int off = 32; off > 0; off >>= 1) v += __shfl_xor(v, off, 64);
    return v;
}
__device__ __forceinline__ float wave_reduce_max(float v) {
    #pragma unroll
    for (int off = 32; off > 0; off >>= 1) v = fmaxf(v, __shfl_xor(v, off, 64));
    return v;
}
__device__ __forceinline__ int wave_reduce_sum_i(int v) {
    #pragma unroll
    for (int off = 32; off > 0; off >>= 1) v += __shfl_xor(v, off, 64);
    return v;
}
__device__ __forceinline__ int wave_scan_incl_i(int v) {
    int lane = threadIdx.x & 63;
    #pragma unroll
    for (int off = 1; off < 64; off <<= 1) {
        int t = __shfl_up(v, off, 64);
        if (lane >= off) v += t;
    }
    return v;
}

__device__ __forceinline__ short f2bf(float f) {           // RNE f32->bf16
    unsigned u = __float_as_uint(f);
    u += 0x7fffu + ((u >> 16) & 1u);
    return (short)(u >> 16);
}
__device__ __forceinline__ float bflo(unsigned p) { return __uint_as_float(p << 16); }
__device__ __forceinline__ float bfhi(unsigned p) { return __uint_as_float(p & 0xffff0000u); }

// ---- prep: v_src/v_dst GEMV weights (W @ att), combined layer-2 bias ----
__global__ void prep_kernel(const float* __restrict__ Wsrc1, const float* __restrict__ att_src1,
                            const float* __restrict__ Wdst1, const float* __restrict__ att_dst1,
                            const float* __restrict__ Wsrc2, const float* __restrict__ att_src2,
                            const float* __restrict__ Wdst2, const float* __restrict__ att_dst2,
                            const float* __restrict__ b2, const float* __restrict__ b_lin2,
                            float* v_src1, float* v_dst1, float* v_src2, float* v_dst2,
                            float* bsum2) {
    int t = threadIdx.x;
    if (t < D_IN) {
        float s1 = 0.f, s2 = 0.f;
        for (int c = 0; c < HID; c++) {
            s1 += Wsrc1[t * HID + c] * att_src1[c];
            s2 += Wdst1[t * HID + c] * att_dst1[c];
        }
        v_src1[t] = s1; v_dst1[t] = s2;
    }
    if (t < HID) {
        float s1 = 0.f, s2 = 0.f;
        for (int c = 0; c < D_OUT; c++) {
            s1 += Wsrc2[t * D_OUT + c] * att_src2[c];
            s2 += Wdst2[t * D_OUT + c] * att_dst2[c];
        }
        v_src2[t] = s1; v_dst2[t] = s2;
    }
    if (t < D_OUT) bsum2[t] = b2[t] + b_lin2[t];
}

// ---- pack [Wa | Wb] into bf16 B-fragment stream ----
// Wp[((s*NTG + nt)*64 + lane)*8 + j] = W[k][col], k = s*32 + (lane>>4)*8 + j,
// cg = nt*16 + (lane&15); cg < NH -> Wa col cg, else Wb col cg-NH.
__global__ void pack_kernel(const float* __restrict__ Wa, const float* __restrict__ Wb,
                            short* __restrict__ Wp, int NTG, int NH, int total) {
    int idx = blockIdx.x * 256 + threadIdx.x;
    if (idx >= total) return;
    int j = idx & 7;
    int lane = (idx >> 3) & 63;
    int r = idx >> 9;
    int nt = r % NTG;
    int s = r / NTG;
    int k = s * 32 + ((lane >> 4) * 8) + j;
    int cg = nt * 16 + (lane & 15);
    const float* W = (cg < NH) ? Wa : Wb;
    int col = (cg < NH) ? cg : cg - NH;
    Wp[idx] = f2bf(W[(size_t)k * NH + col]);
}

// ---- CSR build ----
__global__ void hist_kernel(const int* __restrict__ dst, int E, int* deg) {
    int e = blockIdx.x * 256 + threadIdx.x;
    if (e < E) atomicAdd(&deg[dst[e]], 1);
}

__global__ void scan_partial(const int* __restrict__ deg, int n, int* bsums) {
    __shared__ int ws[16];
    int i = blockIdx.x * 1024 + threadIdx.x;
    int v = (i < n) ? deg[i] : 0;
    int s = wave_reduce_sum_i(v);
    if ((threadIdx.x & 63) == 0) ws[threadIdx.x >> 6] = s;
    __syncthreads();
    if (threadIdx.x == 0) {
        int tot = 0;
        #pragma unroll
        for (int w = 0; w < 16; w++) tot += ws[w];
        bsums[blockIdx.x] = tot;
    }
}

__global__ void scan_offsets(const int* __restrict__ bsums, int nb, int* boff) {
    int lane = threadIdx.x;
    int v = (lane < nb) ? bsums[lane] : 0;
    int incl = wave_scan_incl_i(v);
    if (lane < nb) boff[lane] = incl - v;
}

__global__ void scan_final(const int* __restrict__ deg, int n, const int* __restrict__ boff,
                           int* row_ptr, int* cursor) {
    __shared__ int ws[16];
    int i = blockIdx.x * 1024 + threadIdx.x;
    int wid = threadIdx.x >> 6;
    int v = (i < n) ? deg[i] : 0;
    int sv = wave_scan_incl_i(v);
    if ((threadIdx.x & 63) == 63) ws[wid] = sv;
    __syncthreads();
    if (threadIdx.x == 0) {
        int run = 0;
        #pragma unroll
        for (int w = 0; w < 16; w++) { int t = ws[w]; ws[w] = run; run += t; }
    }
    __syncthreads();
    int excl = boff[blockIdx.x] + ws[wid] + sv - v;
    if (i < n) {
        row_ptr[i] = excl; cursor[i] = excl;
        if (i == n - 1) row_ptr[n] = excl + v;
    }
}

__global__ void scatter_kernel(const int* __restrict__ src, const int* __restrict__ dst, int E,
                               int* cursor, int* ssrc) {
    int e = blockIdx.x * 256 + threadIdx.x;
    if (e < E) {
        int d = dst[e];
        int pos = atomicAdd(&cursor[d], 1);
        ssrc[pos] = src[e];
    }
}

// ---- MFMA GEMM: block tile 64 rows x (4*NT*16) logical cols; 4 waves side-by-side
// in N (wave tile 64 x NT*16). acc = 4*NT floatx4 (64 VGPR at NT=4). A staged
// fp32->bf16 (AF32) or copied bf16. NH = 2*NT*16; cg < NH -> outb bf16 else outf
// fp32+bias. ATT: fuse a_src/a_dst fp32 dots into A staging.
template <int KS, int NT, bool AF32, bool ATT>
__global__ __launch_bounds__(256, 4) void gemm_t(const void* __restrict__ Av,
                                                 const short* __restrict__ Wp,
                                                 const float* __restrict__ bias,
                                                 const float* __restrict__ vsrc,
                                                 const float* __restrict__ vdst,
                                                 float* __restrict__ a_src,
                                                 float* __restrict__ a_dst,
                                                 unsigned short* __restrict__ outb,
                                                 float* __restrict__ outf, int M) {
    const int K = KS * 32;
    const int NH = NT * 32;                   // half-width (bf16 half = fp32 half)
    const int BS = NT * 4 * 512;              // B_s shorts per k-step (= 2*NH*32)
    __shared__ short A_s[64 * 40];            // 64 rows x 32 bf16, stride 40 (80B)
    __shared__ short B_s[BS];

    int tid = threadIdx.x;
    int wave = tid >> 6, lane = tid & 63;
    int mr = lane & 15, quad = lane >> 4;
    int bm = blockIdx.x * 64;

    floatx4 acc[4][NT];
    #pragma unroll
    for (int i = 0; i < 4; i++)
        #pragma unroll
        for (int j = 0; j < NT; j++) acc[i][j] = (floatx4){0.f, 0.f, 0.f, 0.f};

    int sr = tid >> 2, q = tid & 3;           // A staging: row, 8-elem quarter
    int grow = bm + sr;
    int crow = (grow < M) ? grow : M - 1;
    float psrc = 0.f, pdst = 0.f;

    for (int s = 0; s < KS; s++) {
        if (AF32) {
            const float* ap = (const float*)Av + (size_t)crow * K + s * 32 + q * 8;
            float4 f0 = *(const float4*)(ap + 0);
            float4 f1 = *(const float4*)(ap + 4);
            if (ATT) {
                const float* vs = vsrc + s * 32 + q * 8;
                const float* vd = vdst + s * 32 + q * 8;
                float fa[8] = {f0.x, f0.y, f0.z, f0.w, f1.x, f1.y, f1.z, f1.w};
                #pragma unroll
                for (int i = 0; i < 8; i++) {
                    psrc += fa[i] * vs[i];
                    pdst += fa[i] * vd[i];
                }
            }
            short8 av = {f2bf(f0.x), f2bf(f0.y), f2bf(f0.z), f2bf(f0.w),
                         f2bf(f1.x), f2bf(f1.y), f2bf(f1.z), f2bf(f1.w)};
            *(short8*)&A_s[sr * 40 + q * 8] = av;
        } else {
            const unsigned short* ap = (const unsigned short*)Av + (size_t)crow * K + s * 32 + q * 8;
            *(short8*)&A_s[sr * 40 + q * 8] = *(const short8*)ap;
        }
        {   // B staging: linear copy, BS/256 shorts per thread
            const short* bp = Wp + (size_t)s * BS + tid * (BS / 256);
            short* bq = &B_s[tid * (BS / 256)];
            #pragma unroll
            for (int c = 0; c < BS / 256 / 8; c++)
                *(short8*)(bq + c * 8) = *(const short8*)(bp + c * 8);
        }
        __syncthreads();

        short8 af[4];
        #pragma unroll
        for (int tm = 0; tm < 4; tm++)
            af[tm] = *(const short8*)&A_s[(tm * 16 + mr) * 40 + quad * 8];
        #pragma unroll
        for (int tn = 0; tn < NT; tn++) {
            short8 bfr = *(const short8*)&B_s[((wave * NT + tn) * 64 + lane) * 8];
            #pragma unroll
            for (int tm = 0; tm < 4; tm++)
                acc[tm][tn] = __builtin_amdgcn_mfma_f32_16x16x32_bf16(af[tm], bfr,
                                                                      acc[tm][tn], 0, 0, 0);
        }
        __syncthreads();
    }

    if (ATT) {
        psrc += __shfl_xor(psrc, 1, 64);
        pdst += __shfl_xor(pdst, 1, 64);
        psrc += __shfl_xor(psrc, 2, 64);
        pdst += __shfl_xor(pdst, 2, 64);
        if (q == 0 && grow < M) { a_src[grow] = psrc; a_dst[grow] = pdst; }
    }

    #pragma unroll
    for (int tm = 0; tm < 4; tm++) {
        #pragma unroll
        for (int tn = 0; tn < NT; tn++) {
            int cg = wave * NT * 16 + tn * 16 + mr;    // logical col in [0, 2*NH)
            if (cg < NH) {
                #pragma unroll
                for (int r = 0; r < 4; r++) {
                    int gr = bm + tm * 16 + quad * 4 + r;
                    if (gr < M)
                        outb[(size_t)gr * NH + cg] = (unsigned short)f2bf(acc[tm][tn][r]);
                }
            } else {
                float bv = bias[cg - NH];
                #pragma unroll
                for (int r = 0; r < 4; r++) {
                    int gr = bm + tm * 16 + quad * 4 + r;
                    if (gr < M)
                        outf[(size_t)gr * NH + (cg - NH)] = acc[tm][tn][r] + bv;
                }
            }
        }
    }
}

// ---- layer-1 aggregation: wave per dst node; writes h bf16 + layer-2 att scalars ----
__global__ void agg1_kernel(const int* __restrict__ row_ptr, const int* __restrict__ ssrc,
                            const float* __restrict__ a_src, const float* __restrict__ a_dst,
                            const unsigned short* __restrict__ h1b, const float* __restrict__ b1,
                            const float* __restrict__ lin,
                            const float* __restrict__ vs2, const float* __restrict__ vd2,
                            unsigned short* __restrict__ hb,
                            float* __restrict__ a_src2, float* __restrict__ a_dst2,
                            float* __restrict__ lbuf, int Nn) {
    int node = blockIdx.x * 4 + (threadIdx.x >> 6);
    int lane = threadIdx.x & 63;
    if (node >= Nn) return;
    int beg = row_ptr[node], end = row_ptr[node + 1];
    float ad = a_dst[node];

    float m = -INFINITY;
    for (int j = beg + lane; j < end; j += 64) {
        float l = a_src[ssrc[j]] + ad;
        l = (l > 0.f) ? l : NEG_SLOPE * l;
        lbuf[j] = l;
        m = fmaxf(m, l);
    }
    m = wave_reduce_max(m);

    float ssum = 0.f;
    for (int j = beg + lane; j < end; j += 64) {
        float e = __expf(lbuf[j] - m);
        lbuf[j] = e;
        ssum += e;
    }
    ssum = wave_reduce_sum(ssum);
    float inv = 1.f / (ssum + 1e-16f);

    float ax0 = 0.f, ay0 = 0.f, ax1 = 0.f, ay1 = 0.f;
    int j = beg;
    for (; j + 3 < end; j += 4) {
        float w0 = lbuf[j] * inv, w1 = lbuf[j + 1] * inv;
        float w2 = lbuf[j + 2] * inv, w3 = lbuf[j + 3] * inv;
        int s0 = ssrc[j], s1 = ssrc[j + 1], s2 = ssrc[j + 2], s3 = ssrc[j + 3];
        unsigned p0 = *(const unsigned*)(h1b + (size_t)s0 * HID + lane * 2);
        unsigned p1 = *(const unsigned*)(h1b + (size_t)s1 * HID + lane * 2);
        unsigned p2 = *(const unsigned*)(h1b + (size_t)s2 * HID + lane * 2);
        unsigned p3 = *(const unsigned*)(h1b + (size_t)s3 * HID + lane * 2);
        ax0 += w0 * bflo(p0); ay0 += w0 * bfhi(p0);
        ax1 += w1 * bflo(p1); ay1 += w1 * bfhi(p1);
        ax0 += w2 * bflo(p2); ay0 += w2 * bfhi(p2);
        ax1 += w3 * bflo(p3); ay1 += w3 * bfhi(p3);
    }
    for (; j < end; j++) {
        float w = lbuf[j] * inv;
        unsigned p = *(const unsigned*)(h1b + (size_t)ssrc[j] * HID + lane * 2);
        ax0 += w * bflo(p); ay0 += w * bfhi(p);
    }
    int c = lane * 2;
    const float* lrow = lin + (size_t)node * HID;
    float ox = fmaxf(ax0 + ax1 + b1[c + 0] + lrow[c + 0], 0.f);
    float oy = fmaxf(ay0 + ay1 + b1[c + 1] + lrow[c + 1], 0.f);
    unsigned pk = (unsigned)(unsigned short)f2bf(ox) | ((unsigned)(unsigned short)f2bf(oy) << 16);
    *(unsigned*)&hb[(size_t)node * HID + c] = pk;

    // layer-2 attention scalars from exact fp32 h
    float ps = ox * vs2[c] + oy * vs2[c + 1];
    float pd = ox * vd2[c] + oy * vd2[c + 1];
    ps = wave_reduce_sum(ps);
    pd = wave_reduce_sum(pd);
    if (lane == 0) { a_src2[node] = ps; a_dst2[node] = pd; }
}

// ---- layer-2 aggregation; saves (m, inv) per node for the alpha pass ----
__global__ void agg2_kernel(const int* __restrict__ row_ptr, const int* __restrict__ ssrc,
                            const float* __restrict__ a_src, const float* __restrict__ a_dst,
                            const unsigned short* __restrict__ h2b,
                            float* __restrict__ out, float2* __restrict__ sm2,
                            float* __restrict__ lbuf, int Nn) {
    int node = blockIdx.x * 4 + (threadIdx.x >> 6);
    int lane = threadIdx.x & 63;
    if (node >= Nn) return;
    int beg = row_ptr[node], end = row_ptr[node + 1];
    float ad = a_dst[node];

    float m = -INFINITY;
    for (int j = beg + lane; j < end; j += 64) {
        float l = a_src[ssrc[j]] + ad;
        l = (l > 0.f) ? l : NEG_SLOPE * l;
        lbuf[j] = l;
        m = fmaxf(m, l);
    }
    m = wave_reduce_max(m);

    float ssum = 0.f;
    for (int j = beg + lane; j < end; j += 64) {
        float e = __expf(lbuf[j] - m);
        lbuf[j] = e;
        ssum += e;
    }
    ssum = wave_reduce_sum(ssum);
    float inv = 1.f / (ssum + 1e-16f);
    if (lane == 0) sm2[node] = make_float2(m, inv);

    float a0 = 0.f, a1 = 0.f;
    int j = beg;
    for (; j + 3 < end; j += 4) {
        float w0 = lbuf[j] * inv, w1 = lbuf[j + 1] * inv;
        float w2 = lbuf[j + 2] * inv, w3 = lbuf[j + 3] * inv;
        unsigned short q0 = h2b[(size_t)ssrc[j] * D_OUT + lane];
        unsigned short q1 = h2b[(size_t)ssrc[j + 1] * D_OUT + lane];
        unsigned short q2 = h2b[(size_t)ssrc[j + 2] * D_OUT + lane];
        unsigned short q3 = h2b[(size_t)ssrc[j + 3] * D_OUT + lane];
        a0 += w0 * __uint_as_float((unsigned)q0 << 16);
        a1 += w1 * __uint_as_float((unsigned)q1 << 16);
        a0 += w2 * __uint_as_float((unsigned)q2 << 16);
        a1 += w3 * __uint_as_float((unsigned)q3 << 16);
    }
    for (; j < end; j++) {
        float w = lbuf[j] * inv;
        a0 += w * __uint_as_float((unsigned)h2b[(size_t)ssrc[j] * D_OUT + lane] << 16);
    }
    float* orow = out + (size_t)node * D_OUT;
    orow[lane] = a0 + a1 + orow[lane];
}

// ---- alpha in original edge order: coalesced reads/writes, L2-resident tables ----
__global__ void alpha_kernel(const int* __restrict__ src, const int* __restrict__ dst,
                             const float* __restrict__ a_src2, const float* __restrict__ a_dst2,
                             const float2* __restrict__ sm2, float* __restrict__ alpha, int E) {
    int e = blockIdx.x * 256 + threadIdx.x;
    if (e >= E) return;
    int s = src[e], d = dst[e];
    float l = a_src2[s] + a_dst2[d];
    l = (l > 0.f) ? l : NEG_SLOPE * l;
    float2 mi = sm2[d];
    alpha[e] = __expf(l - mi.x) * mi.y;
}

extern "C" void kernel_launch(void* const* d_in, const int* in_sizes, int n_in,
                              void* d_out, int out_size, void* d_ws, size_t ws_size,
                              hipStream_t stream) {
    const float* x        = (const float*)d_in[0];
    const int*   ei       = (const int*)d_in[1];
    const float* W_src1   = (const float*)d_in[2];
    const float* W_dst1   = (const float*)d_in[3];
    const float* att_src1 = (const float*)d_in[4];
    const float* att_dst1 = (const float*)d_in[5];
    const float* b1       = (const float*)d_in[6];
    const float* W_lin1   = (const float*)d_in[7];
    const float* b_lin1   = (const float*)d_in[8];
    const float* W_src2   = (const float*)d_in[9];
    const float* W_dst2   = (const float*)d_in[10];
    const float* att_src2 = (const float*)d_in[11];
    const float* att_dst2 = (const float*)d_in[12];
    const float* b2       = (const float*)d_in[13];
    const float* W_lin2   = (const float*)d_in[14];
    const float* b_lin2   = (const float*)d_in[15];

    const int Nn = in_sizes[0] / D_IN;   // 50000
    const int E  = in_sizes[1] / 2;      // 800000
    const int* src = ei;
    const int* dst = ei + E;

    char* w = (char*)d_ws;
    auto alloc = [&](size_t bytes) { char* p = w; w += (bytes + 255) & ~(size_t)255; return p; };
    unsigned short* h1b = (unsigned short*)alloc((size_t)Nn * HID * 2);   // bf16 h_src1
    float* lin1   = (float*)alloc((size_t)Nn * HID * 4);                  // x@W_lin1 + b_lin1
    unsigned short* hb  = (unsigned short*)alloc((size_t)Nn * HID * 2);   // bf16 h (layer-1 out)
    unsigned short* h2b = (unsigned short*)alloc((size_t)Nn * D_OUT * 2); // bf16 h_src2
    float* lbuf   = (float*)alloc((size_t)E * 4);
    float* a_src1 = (float*)alloc((size_t)Nn * 4);
    float* a_dst1 = (float*)alloc((size_t)Nn * 4);
    float* a_src2 = (float*)alloc((size_t)Nn * 4);
    float* a_dst2 = (float*)alloc((size_t)Nn * 4);
    float2* sm2   = (float2*)alloc((size_t)Nn * 8);
    int*   deg    = (int*)alloc((size_t)Nn * 4);
    int*   row_ptr= (int*)alloc((size_t)(Nn + 1) * 4);
    int*   cursor = (int*)alloc((size_t)Nn * 4);
    int*   ssrc   = (int*)alloc((size_t)E * 4);
    short* Wp1    = (short*)alloc((size_t)8 * 16 * 512 * 2);  // 128 KB
    short* Wp2    = (short*)alloc((size_t)4 * 8 * 512 * 2);   // 32 KB
    float* v_src1 = (float*)alloc(D_IN * 4);
    float* v_dst1 = (float*)alloc(D_IN * 4);
    float* v_src2 = (float*)alloc(HID * 4);
    float* v_dst2 = (float*)alloc(HID * 4);
    float* bsum2  = (float*)alloc(D_OUT * 4);
    int*   bsums  = (int*)alloc(64 * 4);
    int*   boff   = (int*)alloc(64 * 4);

    float* out       = (float*)d_out;
    float* alpha_out = out + (size_t)Nn * D_OUT;

    prep_kernel<<<1, 256, 0, stream>>>(W_src1, att_src1, W_dst1, att_dst1,
                                       W_src2, att_src2, W_dst2, att_dst2,
                                       b2, b_lin2, v_src1, v_dst1, v_src2, v_dst2, bsum2);
    pack_kernel<<<256, 256, 0, stream>>>(W_src1, W_lin1, Wp1, 16, HID, 8 * 16 * 512);
    pack_kernel<<<64, 256, 0, stream>>>(W_src2, W_lin2, Wp2, 8, D_OUT, 4 * 8 * 512);

    hipMemsetAsync(deg, 0, (size_t)Nn * 4, stream);
    int eblocks = (E + 255) / 256;
    hist_kernel<<<eblocks, 256, 0, stream>>>(dst, E, deg);
    int nb = (Nn + 1023) / 1024;
    scan_partial<<<nb, 1024, 0, stream>>>(deg, Nn, bsums);
    scan_offsets<<<1, 64, 0, stream>>>(bsums, nb, boff);
    scan_final<<<nb, 1024, 0, stream>>>(deg, Nn, boff, row_ptr, cursor);
    scatter_kernel<<<eblocks, 256, 0, stream>>>(src, dst, E, cursor, ssrc);

    int mblocks = (Nn + 63) / 64;   // 782
    gemm_t<8, 4, true, true><<<mblocks, 256, 0, stream>>>(x, Wp1, b_lin1, v_src1, v_dst1,
                                                          a_src1, a_dst1, h1b, lin1, Nn);

    int ablocks = (Nn + 3) / 4;
    agg1_kernel<<<ablocks, 256, 0, stream>>>(row_ptr, ssrc, a_src1, a_dst1, h1b, b1, lin1,
                                             v_src2, v_dst2, hb, a_src2, a_dst2, lbuf, Nn);

    gemm_t<4, 2, false, false><<<mblocks, 256, 0, stream>>>(hb, Wp2, bsum2, nullptr, nullptr,
                                                            nullptr, nullptr, h2b, out, Nn);
    agg2_kernel<<<ablocks, 256, 0, stream>>>(row_ptr, ssrc, a_src2, a_dst2, h2b,
                                             out, sm2, lbuf, Nn);
    alpha_kernel<<<eblocks, 256, 0, stream>>>(src, dst, a_src2, a_dst2, sm2, alpha_out, E);
}

// Round 6
// 352.596 us; speedup vs baseline: 1.8389x; 1.0703x over previous
//
#include <hip/hip_runtime.h>
#include <math.h>

#define D_IN 256
#define HID 128
#define D_OUT 64
#define NEG_SLOPE 0.2f

typedef short short8 __attribute__((ext_vector_type(8)));
typedef float floatx4 __attribute__((ext_vector_type(4)));

__device__ __forceinline__ float wave_reduce_sum(float v) {
    #pragma unroll
    for (int off = 32; off > 0; off >>= 1) v += __shfl_xor(v, off, 64);
    return v;
}
__device__ __forceinline__ float wave_reduce_max(float v) {
    #pragma unroll
    for (int off = 32; off > 0; off >>= 1) v = fmaxf(v, __shfl_xor(v, off, 64));
    return v;
}
__device__ __forceinline__ int wave_reduce_sum_i(int v) {
    #pragma unroll
    for (int off = 32; off > 0; off >>= 1) v += __shfl_xor(v, off, 64);
    return v;
}
__device__ __forceinline__ int wave_scan_incl_i(int v) {
    int lane = threadIdx.x & 63;
    #pragma unroll
    for (int off = 1; off < 64; off <<= 1) {
        int t = __shfl_up(v, off, 64);
        if (lane >= off) v += t;
    }
    return v;
}

__device__ __forceinline__ short f2bf(float f) {           // RNE f32->bf16
    unsigned u = __float_as_uint(f);
    u += 0x7fffu + ((u >> 16) & 1u);
    return (short)(u >> 16);
}
__device__ __forceinline__ float bflo(unsigned p) { return __uint_as_float(p << 16); }
__device__ __forceinline__ float bfhi(unsigned p) { return __uint_as_float(p & 0xffff0000u); }

// ---- prep: GEMV att weights, folded biases ----
__global__ void prep_kernel(const float* __restrict__ Wsrc1, const float* __restrict__ att_src1,
                            const float* __restrict__ Wdst1, const float* __restrict__ att_dst1,
                            const float* __restrict__ Wsrc2, const float* __restrict__ att_src2,
                            const float* __restrict__ Wdst2, const float* __restrict__ att_dst2,
                            const float* __restrict__ b1, const float* __restrict__ b_lin1,
                            const float* __restrict__ b2, const float* __restrict__ b_lin2,
                            float* v_src1, float* v_dst1, float* v_src2, float* v_dst2,
                            float* bsum1, float* bsum2) {
    int t = threadIdx.x;
    if (t < D_IN) {
        float s1 = 0.f, s2 = 0.f;
        for (int c = 0; c < HID; c++) {
            s1 += Wsrc1[t * HID + c] * att_src1[c];
            s2 += Wdst1[t * HID + c] * att_dst1[c];
        }
        v_src1[t] = s1; v_dst1[t] = s2;
    }
    if (t < HID) {
        float s1 = 0.f, s2 = 0.f;
        for (int c = 0; c < D_OUT; c++) {
            s1 += Wsrc2[t * D_OUT + c] * att_src2[c];
            s2 += Wdst2[t * D_OUT + c] * att_dst2[c];
        }
        v_src2[t] = s1; v_dst2[t] = s2;
        bsum1[t] = b1[t] + b_lin1[t];
    }
    if (t < D_OUT) bsum2[t] = b2[t] + b_lin2[t];
}

// ---- pack [Wa | Wb] into bf16 B-fragment stream ----
// Wp[((s*NTG + nt)*64 + lane)*8 + j] = W[k][col], k = s*32 + (lane>>4)*8 + j,
// cg = nt*16 + (lane&15); cg < NH -> Wa col cg, else Wb col cg-NH.
__global__ void pack_kernel(const float* __restrict__ Wa, const float* __restrict__ Wb,
                            short* __restrict__ Wp, int NTG, int NH, int total) {
    int idx = blockIdx.x * 256 + threadIdx.x;
    if (idx >= total) return;
    int j = idx & 7;
    int lane = (idx >> 3) & 63;
    int r = idx >> 9;
    int nt = r % NTG;
    int s = r / NTG;
    int k = s * 32 + ((lane >> 4) * 8) + j;
    int cg = nt * 16 + (lane & 15);
    const float* W = (cg < NH) ? Wa : Wb;
    int col = (cg < NH) ? cg : cg - NH;
    Wp[idx] = f2bf(W[(size_t)k * NH + col]);
}

// ---- CSR build ----
__global__ void hist_kernel(const int* __restrict__ dst, int E, int* deg) {
    int e = blockIdx.x * 256 + threadIdx.x;
    if (e < E) atomicAdd(&deg[dst[e]], 1);
}

__global__ void scan_partial(const int* __restrict__ deg, int n, int* bsums) {
    __shared__ int ws[16];
    int i = blockIdx.x * 1024 + threadIdx.x;
    int v = (i < n) ? deg[i] : 0;
    int s = wave_reduce_sum_i(v);
    if ((threadIdx.x & 63) == 0) ws[threadIdx.x >> 6] = s;
    __syncthreads();
    if (threadIdx.x == 0) {
        int tot = 0;
        #pragma unroll
        for (int w = 0; w < 16; w++) tot += ws[w];
        bsums[blockIdx.x] = tot;
    }
}

__global__ void scan_offsets(const int* __restrict__ bsums, int nb, int* boff) {
    int lane = threadIdx.x;
    int v = (lane < nb) ? bsums[lane] : 0;
    int incl = wave_scan_incl_i(v);
    if (lane < nb) boff[lane] = incl - v;
}

__global__ void scan_final(const int* __restrict__ deg, int n, const int* __restrict__ boff,
                           int* row_ptr, int* cursor) {
    __shared__ int ws[16];
    int i = blockIdx.x * 1024 + threadIdx.x;
    int wid = threadIdx.x >> 6;
    int v = (i < n) ? deg[i] : 0;
    int sv = wave_scan_incl_i(v);
    if ((threadIdx.x & 63) == 63) ws[wid] = sv;
    __syncthreads();
    if (threadIdx.x == 0) {
        int run = 0;
        #pragma unroll
        for (int w = 0; w < 16; w++) { int t = ws[w]; ws[w] = run; run += t; }
    }
    __syncthreads();
    int excl = boff[blockIdx.x] + ws[wid] + sv - v;
    if (i < n) {
        row_ptr[i] = excl; cursor[i] = excl;
        if (i == n - 1) row_ptr[n] = excl + v;
    }
}

__global__ void scatter_kernel(const int* __restrict__ src, const int* __restrict__ dst, int E,
                               int* cursor, int* ssrc) {
    int e = blockIdx.x * 256 + threadIdx.x;
    if (e < E) {
        int d = dst[e];
        int pos = atomicAdd(&cursor[d], 1);
        ssrc[pos] = src[e];
    }
}

// ---- MFMA GEMM with register-prefetch pipeline ----
// Block tile 64 rows x (4*NT*16) logical cols; 4 waves side-by-side in N.
// Both output halves bf16: cg<NH -> outb (no bias), else outc (bias added).
// AF32: A fp32 -> bf16 in staging; ATT: fuse a_src/a_dst fp32 dots.
template <int KS, int NT, bool AF32, bool ATT>
__global__ __launch_bounds__(256, 3) void gemm_t(const void* __restrict__ Av,
                                                 const short* __restrict__ Wp,
                                                 const float* __restrict__ bias,
                                                 const float* __restrict__ vsrc,
                                                 const float* __restrict__ vdst,
                                                 float* __restrict__ a_src,
                                                 float* __restrict__ a_dst,
                                                 unsigned short* __restrict__ outb,
                                                 unsigned short* __restrict__ outc, int M) {
    const int K = KS * 32;
    const int NH = NT * 32;                   // half-width in columns
    const int BS = NT * 4 * 512;              // B shorts per k-step
    const int BPT = BS / 256;                 // B shorts per thread
    __shared__ short A_s[64 * 40];            // 64 rows x 32 bf16, stride 40 (80B)
    __shared__ short B_s[BS];

    int tid = threadIdx.x;
    int wave = tid >> 6, lane = tid & 63;
    int mr = lane & 15, quad = lane >> 4;
    int bm = blockIdx.x * 64;

    floatx4 acc[4][NT];
    #pragma unroll
    for (int i = 0; i < 4; i++)
        #pragma unroll
        for (int j = 0; j < NT; j++) acc[i][j] = (floatx4){0.f, 0.f, 0.f, 0.f};

    int sr = tid >> 2, q = tid & 3;           // A staging: row, 8-elem quarter
    int grow = bm + sr;
    int crow = (grow < M) ? grow : M - 1;
    float psrc = 0.f, pdst = 0.f;

    const float* af32 = (const float*)Av + (size_t)crow * K + q * 8;
    const unsigned short* abf = (const unsigned short*)Av + (size_t)crow * K + q * 8;
    const short* bbase = Wp + tid * BPT;

    float4 fr0, fr1;
    short8 ar;
    short8 breg[BPT / 8];

    if (AF32) { fr0 = *(const float4*)af32; fr1 = *(const float4*)(af32 + 4); }
    else ar = *(const short8*)abf;
    #pragma unroll
    for (int c = 0; c < BPT / 8; c++) breg[c] = *(const short8*)(bbase + c * 8);

    for (int s = 0; s < KS; s++) {
        if (AF32) {
            if (ATT) {
                const float* vs = vsrc + s * 32 + q * 8;
                const float* vd = vdst + s * 32 + q * 8;
                float fa[8] = {fr0.x, fr0.y, fr0.z, fr0.w, fr1.x, fr1.y, fr1.z, fr1.w};
                #pragma unroll
                for (int i = 0; i < 8; i++) { psrc += fa[i] * vs[i]; pdst += fa[i] * vd[i]; }
            }
            short8 av = {f2bf(fr0.x), f2bf(fr0.y), f2bf(fr0.z), f2bf(fr0.w),
                         f2bf(fr1.x), f2bf(fr1.y), f2bf(fr1.z), f2bf(fr1.w)};
            *(short8*)&A_s[sr * 40 + q * 8] = av;
        } else {
            *(short8*)&A_s[sr * 40 + q * 8] = ar;
        }
        #pragma unroll
        for (int c = 0; c < BPT / 8; c++) *(short8*)&B_s[tid * BPT + c * 8] = breg[c];
        __syncthreads();

        if (s + 1 < KS) {        // prefetch next step; overlaps MFMA below
            if (AF32) {
                fr0 = *(const float4*)(af32 + (s + 1) * 32);
                fr1 = *(const float4*)(af32 + (s + 1) * 32 + 4);
            } else {
                ar = *(const short8*)(abf + (s + 1) * 32);
            }
            #pragma unroll
            for (int c = 0; c < BPT / 8; c++)
                breg[c] = *(const short8*)(bbase + (size_t)(s + 1) * BS + c * 8);
        }

        short8 af[4];
        #pragma unroll
        for (int tm = 0; tm < 4; tm++)
            af[tm] = *(const short8*)&A_s[(tm * 16 + mr) * 40 + quad * 8];
        #pragma unroll
        for (int tn = 0; tn < NT; tn++) {
            short8 bfr = *(const short8*)&B_s[((wave * NT + tn) * 64 + lane) * 8];
            #pragma unroll
            for (int tm = 0; tm < 4; tm++)
                acc[tm][tn] = __builtin_amdgcn_mfma_f32_16x16x32_bf16(af[tm], bfr,
                                                                      acc[tm][tn], 0, 0, 0);
        }
        __syncthreads();
    }

    if (ATT) {
        psrc += __shfl_xor(psrc, 1, 64);
        pdst += __shfl_xor(pdst, 1, 64);
        psrc += __shfl_xor(psrc, 2, 64);
        pdst += __shfl_xor(pdst, 2, 64);
        if (q == 0 && grow < M) { a_src[grow] = psrc; a_dst[grow] = pdst; }
    }

    #pragma unroll
    for (int tm = 0; tm < 4; tm++) {
        #pragma unroll
        for (int tn = 0; tn < NT; tn++) {
            int cg = wave * NT * 16 + tn * 16 + mr;    // logical col in [0, 2*NH)
            if (cg < NH) {
                #pragma unroll
                for (int r = 0; r < 4; r++) {
                    int gr = bm + tm * 16 + quad * 4 + r;
                    if (gr < M)
                        outb[(size_t)gr * NH + cg] = (unsigned short)f2bf(acc[tm][tn][r]);
                }
            } else {
                float bv = bias[cg - NH];
                #pragma unroll
                for (int r = 0; r < 4; r++) {
                    int gr = bm + tm * 16 + quad * 4 + r;
                    if (gr < M)
                        outc[(size_t)gr * NH + (cg - NH)] = (unsigned short)f2bf(acc[tm][tn][r] + bv);
                }
            }
        }
    }
}

// ---- layer-1 agg: online softmax + half-wave-per-edge gather; emits h bf16 + L2 scalars ----
__global__ void agg1_kernel(const int* __restrict__ row_ptr, const int* __restrict__ ssrc,
                            const float* __restrict__ a_src, const float* __restrict__ a_dst,
                            const unsigned short* __restrict__ h1b,
                            const unsigned short* __restrict__ linb,
                            const float* __restrict__ vs2, const float* __restrict__ vd2,
                            unsigned short* __restrict__ hb,
                            float* __restrict__ a_src2, float* __restrict__ a_dst2,
                            float* __restrict__ lbuf, int Nn) {
    int node = blockIdx.x * 4 + (threadIdx.x >> 6);
    int lane = threadIdx.x & 63;
    if (node >= Nn) return;
    int beg = row_ptr[node], end = row_ptr[node + 1];
    float ad = a_dst[node];

    float ml = -INFINITY, sl = 0.f;
    for (int j = beg + lane; j < end; j += 64) {
        float l = a_src[ssrc[j]] + ad;
        l = (l > 0.f) ? l : NEG_SLOPE * l;
        lbuf[j] = l;
        if (l > ml) { sl = sl * __expf(ml - l) + 1.f; ml = l; }
        else sl += __expf(l - ml);
    }
    float m = wave_reduce_max(ml);
    float sc = (sl > 0.f) ? sl * __expf(ml - m) : 0.f;
    float ssum = wave_reduce_sum(sc);
    float inv = 1.f / (ssum + 1e-16f);

    int half = lane >> 5, cl = lane & 31;
    float4 acc = make_float4(0.f, 0.f, 0.f, 0.f);
    const unsigned short* hcol = h1b + cl * 4;
    int j = beg + half;
    for (; j + 2 < end; j += 4) {
        float w0 = __expf(lbuf[j] - m) * inv;
        float w1 = __expf(lbuf[j + 2] - m) * inv;
        int s0 = ssrc[j], s1 = ssrc[j + 2];
        uint2 p0 = *(const uint2*)(hcol + (size_t)s0 * HID);
        uint2 p1 = *(const uint2*)(hcol + (size_t)s1 * HID);
        acc.x += w0 * bflo(p0.x); acc.y += w0 * bfhi(p0.x);
        acc.z += w0 * bflo(p0.y); acc.w += w0 * bfhi(p0.y);
        acc.x += w1 * bflo(p1.x); acc.y += w1 * bfhi(p1.x);
        acc.z += w1 * bflo(p1.y); acc.w += w1 * bfhi(p1.y);
    }
    for (; j < end; j += 2) {
        float w = __expf(lbuf[j] - m) * inv;
        uint2 p = *(const uint2*)(hcol + (size_t)ssrc[j] * HID);
        acc.x += w * bflo(p.x); acc.y += w * bfhi(p.x);
        acc.z += w * bflo(p.y); acc.w += w * bfhi(p.y);
    }
    acc.x += __shfl_xor(acc.x, 32, 64);
    acc.y += __shfl_xor(acc.y, 32, 64);
    acc.z += __shfl_xor(acc.z, 32, 64);
    acc.w += __shfl_xor(acc.w, 32, 64);

    int c = cl * 4;
    uint2 lb = *(const uint2*)(linb + (size_t)node * HID + c);
    float o0 = fmaxf(acc.x + bflo(lb.x), 0.f);
    float o1 = fmaxf(acc.y + bfhi(lb.x), 0.f);
    float o2 = fmaxf(acc.z + bflo(lb.y), 0.f);
    float o3 = fmaxf(acc.w + bfhi(lb.y), 0.f);
    if (half == 0) {
        uint2 pk;
        pk.x = (unsigned)(unsigned short)f2bf(o0) | ((unsigned)(unsigned short)f2bf(o1) << 16);
        pk.y = (unsigned)(unsigned short)f2bf(o2) | ((unsigned)(unsigned short)f2bf(o3) << 16);
        *(uint2*)&hb[(size_t)node * HID + c] = pk;
    }
    float ps = o0 * vs2[c] + o1 * vs2[c + 1] + o2 * vs2[c + 2] + o3 * vs2[c + 3];
    float pd = o0 * vd2[c] + o1 * vd2[c + 1] + o2 * vd2[c + 2] + o3 * vd2[c + 3];
    ps = wave_reduce_sum(ps) * 0.5f;   // halves are duplicated after the xor-combine
    pd = wave_reduce_sum(pd) * 0.5f;
    if (lane == 0) { a_src2[node] = ps; a_dst2[node] = pd; }
}

// ---- layer-2 agg: online softmax + quarter-wave-per-edge; writes out directly ----
__global__ void agg2_kernel(const int* __restrict__ row_ptr, const int* __restrict__ ssrc,
                            const float* __restrict__ a_src, const float* __restrict__ a_dst,
                            const unsigned short* __restrict__ h2b,
                            const unsigned short* __restrict__ lin2b,
                            float* __restrict__ out, float2* __restrict__ sm2,
                            float* __restrict__ lbuf, int Nn) {
    int node = blockIdx.x * 4 + (threadIdx.x >> 6);
    int lane = threadIdx.x & 63;
    if (node >= Nn) return;
    int beg = row_ptr[node], end = row_ptr[node + 1];
    float ad = a_dst[node];

    float ml = -INFINITY, sl = 0.f;
    for (int j = beg + lane; j < end; j += 64) {
        float l = a_src[ssrc[j]] + ad;
        l = (l > 0.f) ? l : NEG_SLOPE * l;
        lbuf[j] = l;
        if (l > ml) { sl = sl * __expf(ml - l) + 1.f; ml = l; }
        else sl += __expf(l - ml);
    }
    float m = wave_reduce_max(ml);
    float sc = (sl > 0.f) ? sl * __expf(ml - m) : 0.f;
    float ssum = wave_reduce_sum(sc);
    float inv = 1.f / (ssum + 1e-16f);
    if (lane == 0) sm2[node] = make_float2(m, inv);

    int qh = lane >> 4, cl = lane & 15;
    float4 acc = make_float4(0.f, 0.f, 0.f, 0.f);
    const unsigned short* hcol = h2b + cl * 4;
    int j = beg + qh;
    for (; j + 4 < end; j += 8) {
        float w0 = __expf(lbuf[j] - m) * inv;
        float w1 = __expf(lbuf[j + 4] - m) * inv;
        int s0 = ssrc[j], s1 = ssrc[j + 4];
        uint2 p0 = *(const uint2*)(hcol + (size_t)s0 * D_OUT);
        uint2 p1 = *(const uint2*)(hcol + (size_t)s1 * D_OUT);
        acc.x += w0 * bflo(p0.x); acc.y += w0 * bfhi(p0.x);
        acc.z += w0 * bflo(p0.y); acc.w += w0 * bfhi(p0.y);
        acc.x += w1 * bflo(p1.x); acc.y += w1 * bfhi(p1.x);
        acc.z += w1 * bflo(p1.y); acc.w += w1 * bfhi(p1.y);
    }
    for (; j < end; j += 4) {
        float w = __expf(lbuf[j] - m) * inv;
        uint2 p = *(const uint2*)(hcol + (size_t)ssrc[j] * D_OUT);
        acc.x += w * bflo(p.x); acc.y += w * bfhi(p.x);
        acc.z += w * bflo(p.y); acc.w += w * bfhi(p.y);
    }
    #pragma unroll
    for (int off = 16; off <= 32; off <<= 1) {
        acc.x += __shfl_xor(acc.x, off, 64);
        acc.y += __shfl_xor(acc.y, off, 64);
        acc.z += __shfl_xor(acc.z, off, 64);
        acc.w += __shfl_xor(acc.w, off, 64);
    }
    if (qh == 0) {
        int c = cl * 4;
        uint2 lb = *(const uint2*)(lin2b + (size_t)node * D_OUT + c);
        float4 o = make_float4(acc.x + bflo(lb.x), acc.y + bfhi(lb.x),
                               acc.z + bflo(lb.y), acc.w + bfhi(lb.y));
        *(float4*)&out[(size_t)node * D_OUT + c] = o;
    }
}

// ---- alpha in original edge order ----
__global__ void alpha_kernel(const int* __restrict__ src, const int* __restrict__ dst,
                             const float* __restrict__ a_src2, const float* __restrict__ a_dst2,
                             const float2* __restrict__ sm2, float* __restrict__ alpha, int E) {
    int e = blockIdx.x * 256 + threadIdx.x;
    if (e >= E) return;
    int s = src[e], d = dst[e];
    float l = a_src2[s] + a_dst2[d];
    l = (l > 0.f) ? l : NEG_SLOPE * l;
    float2 mi = sm2[d];
    alpha[e] = __expf(l - mi.x) * mi.y;
}

extern "C" void kernel_launch(void* const* d_in, const int* in_sizes, int n_in,
                              void* d_out, int out_size, void* d_ws, size_t ws_size,
                              hipStream_t stream) {
    const float* x        = (const float*)d_in[0];
    const int*   ei       = (const int*)d_in[1];
    const float* W_src1   = (const float*)d_in[2];
    const float* W_dst1   = (const float*)d_in[3];
    const float* att_src1 = (const float*)d_in[4];
    const float* att_dst1 = (const float*)d_in[5];
    const float* b1       = (const float*)d_in[6];
    const float* W_lin1   = (const float*)d_in[7];
    const float* b_lin1   = (const float*)d_in[8];
    const float* W_src2   = (const float*)d_in[9];
    const float* W_dst2   = (const float*)d_in[10];
    const float* att_src2 = (const float*)d_in[11];
    const float* att_dst2 = (const float*)d_in[12];
    const float* b2       = (const float*)d_in[13];
    const float* W_lin2   = (const float*)d_in[14];
    const float* b_lin2   = (const float*)d_in[15];

    const int Nn = in_sizes[0] / D_IN;   // 50000
    const int E  = in_sizes[1] / 2;      // 800000
    const int* src = ei;
    const int* dst = ei + E;

    char* w = (char*)d_ws;
    auto alloc = [&](size_t bytes) { char* p = w; w += (bytes + 255) & ~(size_t)255; return p; };
    unsigned short* h1b  = (unsigned short*)alloc((size_t)Nn * HID * 2);    // bf16 h_src1
    unsigned short* lin1b= (unsigned short*)alloc((size_t)Nn * HID * 2);    // bf16 lin1+bsum1
    unsigned short* hb   = (unsigned short*)alloc((size_t)Nn * HID * 2);    // bf16 h
    unsigned short* h2b  = (unsigned short*)alloc((size_t)Nn * D_OUT * 2);  // bf16 h_src2
    unsigned short* lin2b= (unsigned short*)alloc((size_t)Nn * D_OUT * 2);  // bf16 lin2+bsum2
    float* lbuf   = (float*)alloc((size_t)E * 4);
    float* a_src1 = (float*)alloc((size_t)Nn * 4);
    float* a_dst1 = (float*)alloc((size_t)Nn * 4);
    float* a_src2 = (float*)alloc((size_t)Nn * 4);
    float* a_dst2 = (float*)alloc((size_t)Nn * 4);
    float2* sm2   = (float2*)alloc((size_t)Nn * 8);
    int*   deg    = (int*)alloc((size_t)Nn * 4);
    int*   row_ptr= (int*)alloc((size_t)(Nn + 1) * 4);
    int*   cursor = (int*)alloc((size_t)Nn * 4);
    int*   ssrc   = (int*)alloc((size_t)E * 4);
    short* Wp1    = (short*)alloc((size_t)8 * 16 * 512 * 2);  // 128 KB
    short* Wp2    = (short*)alloc((size_t)4 * 8 * 512 * 2);   // 32 KB
    float* v_src1 = (float*)alloc(D_IN * 4);
    float* v_dst1 = (float*)alloc(D_IN * 4);
    float* v_src2 = (float*)alloc(HID * 4);
    float* v_dst2 = (float*)alloc(HID * 4);
    float* bsum1  = (float*)alloc(HID * 4);
    float* bsum2  = (float*)alloc(D_OUT * 4);
    int*   bsums  = (int*)alloc(64 * 4);
    int*   boff   = (int*)alloc(64 * 4);

    float* out       = (float*)d_out;
    float* alpha_out = out + (size_t)Nn * D_OUT;

    prep_kernel<<<1, 256, 0, stream>>>(W_src1, att_src1, W_dst1, att_dst1,
                                       W_src2, att_src2, W_dst2, att_dst2,
                                       b1, b_lin1, b2, b_lin2,
                                       v_src1, v_dst1, v_src2, v_dst2, bsum1, bsum2);
    pack_kernel<<<256, 256, 0, stream>>>(W_src1, W_lin1, Wp1, 16, HID, 8 * 16 * 512);
    pack_kernel<<<64, 256, 0, stream>>>(W_src2, W_lin2, Wp2, 8, D_OUT, 4 * 8 * 512);

    hipMemsetAsync(deg, 0, (size_t)Nn * 4, stream);
    int eblocks = (E + 255) / 256;
    hist_kernel<<<eblocks, 256, 0, stream>>>(dst, E, deg);
    int nb = (Nn + 1023) / 1024;
    scan_partial<<<nb, 1024, 0, stream>>>(deg, Nn, bsums);
    scan_offsets<<<1, 64, 0, stream>>>(bsums, nb, boff);
    scan_final<<<nb, 1024, 0, stream>>>(deg, Nn, boff, row_ptr, cursor);
    scatter_kernel<<<eblocks, 256, 0, stream>>>(src, dst, E, cursor, ssrc);

    int mblocks = (Nn + 63) / 64;   // 782
    gemm_t<8, 4, true, true><<<mblocks, 256, 0, stream>>>(x, Wp1, bsum1, v_src1, v_dst1,
                                                          a_src1, a_dst1, h1b, lin1b, Nn);

    int ablocks = (Nn + 3) / 4;
    agg1_kernel<<<ablocks, 256, 0, stream>>>(row_ptr, ssrc, a_src1, a_dst1, h1b, lin1b,
                                             v_src2, v_dst2, hb, a_src2, a_dst2, lbuf, Nn);

    gemm_t<4, 2, false, false><<<mblocks, 256, 0, stream>>>(hb, Wp2, bsum2, nullptr, nullptr,
                                                            nullptr, nullptr, h2b, lin2b, Nn);
    agg2_kernel<<<ablocks, 256, 0, stream>>>(row_ptr, ssrc, a_src2, a_dst2, h2b, lin2b,
                                             out, sm2, lbuf, Nn);
    alpha_kernel<<<eblocks, 256, 0, stream>>>(src, dst, a_src2, a_dst2, sm2, alpha_out, E);
}

// Round 7
// 343.200 us; speedup vs baseline: 1.8893x; 1.0274x over previous
//
#include <hip/hip_runtime.h>
#include <math.h>

#define D_IN 256
#define HID 128
#define D_OUT 64
#define NEG_SLOPE 0.2f

typedef short short8 __attribute__((ext_vector_type(8)));
typedef float floatx4 __attribute__((ext_vector_type(4)));

__device__ __forceinline__ float wave_reduce_sum(float v) {
    #pragma unroll
    for (int off = 32; off > 0; off >>= 1) v += __shfl_xor(v, off, 64);
    return v;
}
__device__ __forceinline__ int wave_reduce_sum_i(int v) {
    #pragma unroll
    for (int off = 32; off > 0; off >>= 1) v += __shfl_xor(v, off, 64);
    return v;
}
__device__ __forceinline__ int wave_scan_incl_i(int v) {
    int lane = threadIdx.x & 63;
    #pragma unroll
    for (int off = 1; off < 64; off <<= 1) {
        int t = __shfl_up(v, off, 64);
        if (lane >= off) v += t;
    }
    return v;
}

__device__ __forceinline__ short f2bf(float f) {           // RNE f32->bf16
    unsigned u = __float_as_uint(f);
    u += 0x7fffu + ((u >> 16) & 1u);
    return (short)(u >> 16);
}
__device__ __forceinline__ float bflo(unsigned p) { return __uint_as_float(p << 16); }
__device__ __forceinline__ float bfhi(unsigned p) { return __uint_as_float(p & 0xffff0000u); }

// ---- prep: GEMV att weights, folded biases ----
__global__ void prep_kernel(const float* __restrict__ Wsrc1, const float* __restrict__ att_src1,
                            const float* __restrict__ Wdst1, const float* __restrict__ att_dst1,
                            const float* __restrict__ Wsrc2, const float* __restrict__ att_src2,
                            const float* __restrict__ Wdst2, const float* __restrict__ att_dst2,
                            const float* __restrict__ b1, const float* __restrict__ b_lin1,
                            const float* __restrict__ b2, const float* __restrict__ b_lin2,
                            float* v_src1, float* v_dst1, float* v_src2, float* v_dst2,
                            float* bsum1, float* bsum2) {
    int t = threadIdx.x;
    if (t < D_IN) {
        float s1 = 0.f, s2 = 0.f;
        for (int c = 0; c < HID; c++) {
            s1 += Wsrc1[t * HID + c] * att_src1[c];
            s2 += Wdst1[t * HID + c] * att_dst1[c];
        }
        v_src1[t] = s1; v_dst1[t] = s2;
    }
    if (t < HID) {
        float s1 = 0.f, s2 = 0.f;
        for (int c = 0; c < D_OUT; c++) {
            s1 += Wsrc2[t * D_OUT + c] * att_src2[c];
            s2 += Wdst2[t * D_OUT + c] * att_dst2[c];
        }
        v_src2[t] = s1; v_dst2[t] = s2;
        bsum1[t] = b1[t] + b_lin1[t];
    }
    if (t < D_OUT) bsum2[t] = b2[t] + b_lin2[t];
}

// ---- pack [Wa | Wb] into bf16 B-fragment stream ----
__global__ void pack_kernel(const float* __restrict__ Wa, const float* __restrict__ Wb,
                            short* __restrict__ Wp, int NTG, int NH, int total) {
    int idx = blockIdx.x * 256 + threadIdx.x;
    if (idx >= total) return;
    int j = idx & 7;
    int lane = (idx >> 3) & 63;
    int r = idx >> 9;
    int nt = r % NTG;
    int s = r / NTG;
    int k = s * 32 + ((lane >> 4) * 8) + j;
    int cg = nt * 16 + (lane & 15);
    const float* W = (cg < NH) ? Wa : Wb;
    int col = (cg < NH) ? cg : cg - NH;
    Wp[idx] = f2bf(W[(size_t)k * NH + col]);
}

// ---- CSR build ----
__global__ void hist_kernel(const int* __restrict__ dst, int E, int* deg) {
    int e = blockIdx.x * 256 + threadIdx.x;
    if (e < E) atomicAdd(&deg[dst[e]], 1);
}

__global__ void scan_partial(const int* __restrict__ deg, int n, int* bsums) {
    __shared__ int ws[16];
    int i = blockIdx.x * 1024 + threadIdx.x;
    int v = (i < n) ? deg[i] : 0;
    int s = wave_reduce_sum_i(v);
    if ((threadIdx.x & 63) == 0) ws[threadIdx.x >> 6] = s;
    __syncthreads();
    if (threadIdx.x == 0) {
        int tot = 0;
        #pragma unroll
        for (int w = 0; w < 16; w++) tot += ws[w];
        bsums[blockIdx.x] = tot;
    }
}

__global__ void scan_offsets(const int* __restrict__ bsums, int nb, int* boff) {
    int lane = threadIdx.x;
    int v = (lane < nb) ? bsums[lane] : 0;
    int incl = wave_scan_incl_i(v);
    if (lane < nb) boff[lane] = incl - v;
}

__global__ void scan_final(const int* __restrict__ deg, int n, const int* __restrict__ boff,
                           int* row_ptr, int* cursor) {
    __shared__ int ws[16];
    int i = blockIdx.x * 1024 + threadIdx.x;
    int wid = threadIdx.x >> 6;
    int v = (i < n) ? deg[i] : 0;
    int sv = wave_scan_incl_i(v);
    if ((threadIdx.x & 63) == 63) ws[wid] = sv;
    __syncthreads();
    if (threadIdx.x == 0) {
        int run = 0;
        #pragma unroll
        for (int w = 0; w < 16; w++) { int t = ws[w]; ws[w] = run; run += t; }
    }
    __syncthreads();
    int excl = boff[blockIdx.x] + ws[wid] + sv - v;
    if (i < n) {
        row_ptr[i] = excl; cursor[i] = excl;
        if (i == n - 1) row_ptr[n] = excl + v;
    }
}

__global__ void scatter_kernel(const int* __restrict__ src, const int* __restrict__ dst, int E,
                               int* cursor, int* ssrc) {
    int e = blockIdx.x * 256 + threadIdx.x;
    if (e < E) {
        int d = dst[e];
        int pos = atomicAdd(&cursor[d], 1);
        ssrc[pos] = src[e];
    }
}

// ---- MFMA GEMM with register-prefetch pipeline (unchanged from R6) ----
template <int KS, int NT, bool AF32, bool ATT>
__global__ __launch_bounds__(256, 3) void gemm_t(const void* __restrict__ Av,
                                                 const short* __restrict__ Wp,
                                                 const float* __restrict__ bias,
                                                 const float* __restrict__ vsrc,
                                                 const float* __restrict__ vdst,
                                                 float* __restrict__ a_src,
                                                 float* __restrict__ a_dst,
                                                 unsigned short* __restrict__ outb,
                                                 unsigned short* __restrict__ outc, int M) {
    const int K = KS * 32;
    const int NH = NT * 32;
    const int BS = NT * 4 * 512;
    const int BPT = BS / 256;
    __shared__ short A_s[64 * 40];
    __shared__ short B_s[BS];

    int tid = threadIdx.x;
    int wave = tid >> 6, lane = tid & 63;
    int mr = lane & 15, quad = lane >> 4;
    int bm = blockIdx.x * 64;

    floatx4 acc[4][NT];
    #pragma unroll
    for (int i = 0; i < 4; i++)
        #pragma unroll
        for (int j = 0; j < NT; j++) acc[i][j] = (floatx4){0.f, 0.f, 0.f, 0.f};

    int sr = tid >> 2, q = tid & 3;
    int grow = bm + sr;
    int crow = (grow < M) ? grow : M - 1;
    float psrc = 0.f, pdst = 0.f;

    const float* af32 = (const float*)Av + (size_t)crow * K + q * 8;
    const unsigned short* abf = (const unsigned short*)Av + (size_t)crow * K + q * 8;
    const short* bbase = Wp + tid * BPT;

    float4 fr0, fr1;
    short8 ar;
    short8 breg[BPT / 8];

    if (AF32) { fr0 = *(const float4*)af32; fr1 = *(const float4*)(af32 + 4); }
    else ar = *(const short8*)abf;
    #pragma unroll
    for (int c = 0; c < BPT / 8; c++) breg[c] = *(const short8*)(bbase + c * 8);

    for (int s = 0; s < KS; s++) {
        if (AF32) {
            if (ATT) {
                const float* vs = vsrc + s * 32 + q * 8;
                const float* vd = vdst + s * 32 + q * 8;
                float fa[8] = {fr0.x, fr0.y, fr0.z, fr0.w, fr1.x, fr1.y, fr1.z, fr1.w};
                #pragma unroll
                for (int i = 0; i < 8; i++) { psrc += fa[i] * vs[i]; pdst += fa[i] * vd[i]; }
            }
            short8 av = {f2bf(fr0.x), f2bf(fr0.y), f2bf(fr0.z), f2bf(fr0.w),
                         f2bf(fr1.x), f2bf(fr1.y), f2bf(fr1.z), f2bf(fr1.w)};
            *(short8*)&A_s[sr * 40 + q * 8] = av;
        } else {
            *(short8*)&A_s[sr * 40 + q * 8] = ar;
        }
        #pragma unroll
        for (int c = 0; c < BPT / 8; c++) *(short8*)&B_s[tid * BPT + c * 8] = breg[c];
        __syncthreads();

        if (s + 1 < KS) {
            if (AF32) {
                fr0 = *(const float4*)(af32 + (s + 1) * 32);
                fr1 = *(const float4*)(af32 + (s + 1) * 32 + 4);
            } else {
                ar = *(const short8*)(abf + (s + 1) * 32);
            }
            #pragma unroll
            for (int c = 0; c < BPT / 8; c++)
                breg[c] = *(const short8*)(bbase + (size_t)(s + 1) * BS + c * 8);
        }

        short8 af[4];
        #pragma unroll
        for (int tm = 0; tm < 4; tm++)
            af[tm] = *(const short8*)&A_s[(tm * 16 + mr) * 40 + quad * 8];
        #pragma unroll
        for (int tn = 0; tn < NT; tn++) {
            short8 bfr = *(const short8*)&B_s[((wave * NT + tn) * 64 + lane) * 8];
            #pragma unroll
            for (int tm = 0; tm < 4; tm++)
                acc[tm][tn] = __builtin_amdgcn_mfma_f32_16x16x32_bf16(af[tm], bfr,
                                                                      acc[tm][tn], 0, 0, 0);
        }
        __syncthreads();
    }

    if (ATT) {
        psrc += __shfl_xor(psrc, 1, 64);
        pdst += __shfl_xor(pdst, 1, 64);
        psrc += __shfl_xor(psrc, 2, 64);
        pdst += __shfl_xor(pdst, 2, 64);
        if (q == 0 && grow < M) { a_src[grow] = psrc; a_dst[grow] = pdst; }
    }

    #pragma unroll
    for (int tm = 0; tm < 4; tm++) {
        #pragma unroll
        for (int tn = 0; tn < NT; tn++) {
            int cg = wave * NT * 16 + tn * 16 + mr;
            if (cg < NH) {
                #pragma unroll
                for (int r = 0; r < 4; r++) {
                    int gr = bm + tm * 16 + quad * 4 + r;
                    if (gr < M)
                        outb[(size_t)gr * NH + cg] = (unsigned short)f2bf(acc[tm][tn][r]);
                }
            } else {
                float bv = bias[cg - NH];
                #pragma unroll
                for (int r = 0; r < 4; r++) {
                    int gr = bm + tm * 16 + quad * 4 + r;
                    if (gr < M)
                        outc[(size_t)gr * NH + (cg - NH)] = (unsigned short)f2bf(acc[tm][tn][r] + bv);
                }
            }
        }
    }
}

// ---- layer-1 agg: SINGLE fused pass (no max subtraction), half-wave per edge ----
__global__ void agg1_kernel(const int* __restrict__ row_ptr, const int* __restrict__ ssrc,
                            const float* __restrict__ a_src, const float* __restrict__ a_dst,
                            const unsigned short* __restrict__ h1b,
                            const unsigned short* __restrict__ linb,
                            const float* __restrict__ vs2, const float* __restrict__ vd2,
                            unsigned short* __restrict__ hb,
                            float* __restrict__ a_src2, float* __restrict__ a_dst2, int Nn) {
    int node = blockIdx.x * 4 + (threadIdx.x >> 6);
    int lane = threadIdx.x & 63;
    if (node >= Nn) return;
    int beg = row_ptr[node], end = row_ptr[node + 1];
    float ad = a_dst[node];

    int half = lane >> 5, cl = lane & 31;
    float4 acc = make_float4(0.f, 0.f, 0.f, 0.f);
    float dsum = 0.f;
    const unsigned short* hcol = h1b + cl * 4;
    int j = beg + half;
    for (; j + 2 < end; j += 4) {
        int s0 = ssrc[j], s1 = ssrc[j + 2];
        float l0 = a_src[s0] + ad; l0 = (l0 > 0.f) ? l0 : NEG_SLOPE * l0;
        float l1 = a_src[s1] + ad; l1 = (l1 > 0.f) ? l1 : NEG_SLOPE * l1;
        float w0 = __expf(l0), w1 = __expf(l1);
        uint2 p0 = *(const uint2*)(hcol + (size_t)s0 * HID);
        uint2 p1 = *(const uint2*)(hcol + (size_t)s1 * HID);
        acc.x += w0 * bflo(p0.x); acc.y += w0 * bfhi(p0.x);
        acc.z += w0 * bflo(p0.y); acc.w += w0 * bfhi(p0.y);
        acc.x += w1 * bflo(p1.x); acc.y += w1 * bfhi(p1.x);
        acc.z += w1 * bflo(p1.y); acc.w += w1 * bfhi(p1.y);
        if (cl == 0) dsum += w0 + w1;
    }
    for (; j < end; j += 2) {
        int s0 = ssrc[j];
        float l = a_src[s0] + ad; l = (l > 0.f) ? l : NEG_SLOPE * l;
        float w = __expf(l);
        uint2 p = *(const uint2*)(hcol + (size_t)s0 * HID);
        acc.x += w * bflo(p.x); acc.y += w * bfhi(p.x);
        acc.z += w * bflo(p.y); acc.w += w * bfhi(p.y);
        if (cl == 0) dsum += w;
    }
    acc.x += __shfl_xor(acc.x, 32, 64);
    acc.y += __shfl_xor(acc.y, 32, 64);
    acc.z += __shfl_xor(acc.z, 32, 64);
    acc.w += __shfl_xor(acc.w, 32, 64);
    dsum = wave_reduce_sum(dsum);
    float inv = 1.f / (dsum + 1e-16f);

    int c = cl * 4;
    uint2 lb = *(const uint2*)(linb + (size_t)node * HID + c);
    float o0 = fmaxf(acc.x * inv + bflo(lb.x), 0.f);
    float o1 = fmaxf(acc.y * inv + bfhi(lb.x), 0.f);
    float o2 = fmaxf(acc.z * inv + bflo(lb.y), 0.f);
    float o3 = fmaxf(acc.w * inv + bfhi(lb.y), 0.f);
    if (half == 0) {
        uint2 pk;
        pk.x = (unsigned)(unsigned short)f2bf(o0) | ((unsigned)(unsigned short)f2bf(o1) << 16);
        pk.y = (unsigned)(unsigned short)f2bf(o2) | ((unsigned)(unsigned short)f2bf(o3) << 16);
        *(uint2*)&hb[(size_t)node * HID + c] = pk;
    }
    float ps = o0 * vs2[c] + o1 * vs2[c + 1] + o2 * vs2[c + 2] + o3 * vs2[c + 3];
    float pd = o0 * vd2[c] + o1 * vd2[c + 1] + o2 * vd2[c + 2] + o3 * vd2[c + 3];
    ps = wave_reduce_sum(ps) * 0.5f;   // halves duplicated after xor-combine
    pd = wave_reduce_sum(pd) * 0.5f;
    if (lane == 0) { a_src2[node] = ps; a_dst2[node] = pd; }
}

// ---- layer-2 agg: SINGLE fused pass, quarter-wave per edge; saves inv for alpha ----
__global__ void agg2_kernel(const int* __restrict__ row_ptr, const int* __restrict__ ssrc,
                            const float* __restrict__ a_src, const float* __restrict__ a_dst,
                            const unsigned short* __restrict__ h2b,
                            const unsigned short* __restrict__ lin2b,
                            float* __restrict__ out, float* __restrict__ sminv, int Nn) {
    int node = blockIdx.x * 4 + (threadIdx.x >> 6);
    int lane = threadIdx.x & 63;
    if (node >= Nn) return;
    int beg = row_ptr[node], end = row_ptr[node + 1];
    float ad = a_dst[node];

    int qh = lane >> 4, cl = lane & 15;
    float4 acc = make_float4(0.f, 0.f, 0.f, 0.f);
    float dsum = 0.f;
    const unsigned short* hcol = h2b + cl * 4;
    int j = beg + qh;
    for (; j + 4 < end; j += 8) {
        int s0 = ssrc[j], s1 = ssrc[j + 4];
        float l0 = a_src[s0] + ad; l0 = (l0 > 0.f) ? l0 : NEG_SLOPE * l0;
        float l1 = a_src[s1] + ad; l1 = (l1 > 0.f) ? l1 : NEG_SLOPE * l1;
        float w0 = __expf(l0), w1 = __expf(l1);
        uint2 p0 = *(const uint2*)(hcol + (size_t)s0 * D_OUT);
        uint2 p1 = *(const uint2*)(hcol + (size_t)s1 * D_OUT);
        acc.x += w0 * bflo(p0.x); acc.y += w0 * bfhi(p0.x);
        acc.z += w0 * bflo(p0.y); acc.w += w0 * bfhi(p0.y);
        acc.x += w1 * bflo(p1.x); acc.y += w1 * bfhi(p1.x);
        acc.z += w1 * bflo(p1.y); acc.w += w1 * bfhi(p1.y);
        if (cl == 0) dsum += w0 + w1;
    }
    for (; j < end; j += 4) {
        int s0 = ssrc[j];
        float l = a_src[s0] + ad; l = (l > 0.f) ? l : NEG_SLOPE * l;
        float w = __expf(l);
        uint2 p = *(const uint2*)(hcol + (size_t)s0 * D_OUT);
        acc.x += w * bflo(p.x); acc.y += w * bfhi(p.x);
        acc.z += w * bflo(p.y); acc.w += w * bfhi(p.y);
        if (cl == 0) dsum += w;
    }
    #pragma unroll
    for (int off = 16; off <= 32; off <<= 1) {
        acc.x += __shfl_xor(acc.x, off, 64);
        acc.y += __shfl_xor(acc.y, off, 64);
        acc.z += __shfl_xor(acc.z, off, 64);
        acc.w += __shfl_xor(acc.w, off, 64);
    }
    dsum = wave_reduce_sum(dsum);
    float inv = 1.f / (dsum + 1e-16f);
    if (lane == 0) sminv[node] = inv;

    if (qh == 0) {
        int c = cl * 4;
        uint2 lb = *(const uint2*)(lin2b + (size_t)node * D_OUT + c);
        float4 o = make_float4(acc.x * inv + bflo(lb.x), acc.y * inv + bfhi(lb.x),
                               acc.z * inv + bflo(lb.y), acc.w * inv + bfhi(lb.y));
        *(float4*)&out[(size_t)node * D_OUT + c] = o;
    }
}

// ---- alpha in original edge order (no max subtraction) ----
__global__ void alpha_kernel(const int* __restrict__ src, const int* __restrict__ dst,
                             const float* __restrict__ a_src2, const float* __restrict__ a_dst2,
                             const float* __restrict__ sminv, float* __restrict__ alpha, int E) {
    int e = blockIdx.x * 256 + threadIdx.x;
    if (e >= E) return;
    int s = src[e], d = dst[e];
    float l = a_src2[s] + a_dst2[d];
    l = (l > 0.f) ? l : NEG_SLOPE * l;
    alpha[e] = __expf(l) * sminv[d];
}

extern "C" void kernel_launch(void* const* d_in, const int* in_sizes, int n_in,
                              void* d_out, int out_size, void* d_ws, size_t ws_size,
                              hipStream_t stream) {
    const float* x        = (const float*)d_in[0];
    const int*   ei       = (const int*)d_in[1];
    const float* W_src1   = (const float*)d_in[2];
    const float* W_dst1   = (const float*)d_in[3];
    const float* att_src1 = (const float*)d_in[4];
    const float* att_dst1 = (const float*)d_in[5];
    const float* b1       = (const float*)d_in[6];
    const float* W_lin1   = (const float*)d_in[7];
    const float* b_lin1   = (const float*)d_in[8];
    const float* W_src2   = (const float*)d_in[9];
    const float* W_dst2   = (const float*)d_in[10];
    const float* att_src2 = (const float*)d_in[11];
    const float* att_dst2 = (const float*)d_in[12];
    const float* b2       = (const float*)d_in[13];
    const float* W_lin2   = (const float*)d_in[14];
    const float* b_lin2   = (const float*)d_in[15];

    const int Nn = in_sizes[0] / D_IN;   // 50000
    const int E  = in_sizes[1] / 2;      // 800000
    const int* src = ei;
    const int* dst = ei + E;

    char* w = (char*)d_ws;
    auto alloc = [&](size_t bytes) { char* p = w; w += (bytes + 255) & ~(size_t)255; return p; };
    unsigned short* h1b  = (unsigned short*)alloc((size_t)Nn * HID * 2);
    unsigned short* lin1b= (unsigned short*)alloc((size_t)Nn * HID * 2);
    unsigned short* hb   = (unsigned short*)alloc((size_t)Nn * HID * 2);
    unsigned short* h2b  = (unsigned short*)alloc((size_t)Nn * D_OUT * 2);
    unsigned short* lin2b= (unsigned short*)alloc((size_t)Nn * D_OUT * 2);
    float* a_src1 = (float*)alloc((size_t)Nn * 4);
    float* a_dst1 = (float*)alloc((size_t)Nn * 4);
    float* a_src2 = (float*)alloc((size_t)Nn * 4);
    float* a_dst2 = (float*)alloc((size_t)Nn * 4);
    float* sminv  = (float*)alloc((size_t)Nn * 4);
    int*   deg    = (int*)alloc((size_t)Nn * 4);
    int*   row_ptr= (int*)alloc((size_t)(Nn + 1) * 4);
    int*   cursor = (int*)alloc((size_t)Nn * 4);
    int*   ssrc   = (int*)alloc((size_t)E * 4);
    short* Wp1    = (short*)alloc((size_t)8 * 16 * 512 * 2);  // 128 KB
    short* Wp2    = (short*)alloc((size_t)4 * 8 * 512 * 2);   // 32 KB
    float* v_src1 = (float*)alloc(D_IN * 4);
    float* v_dst1 = (float*)alloc(D_IN * 4);
    float* v_src2 = (float*)alloc(HID * 4);
    float* v_dst2 = (float*)alloc(HID * 4);
    float* bsum1  = (float*)alloc(HID * 4);
    float* bsum2  = (float*)alloc(D_OUT * 4);
    int*   bsums  = (int*)alloc(64 * 4);
    int*   boff   = (int*)alloc(64 * 4);

    float* out       = (float*)d_out;
    float* alpha_out = out + (size_t)Nn * D_OUT;

    prep_kernel<<<1, 256, 0, stream>>>(W_src1, att_src1, W_dst1, att_dst1,
                                       W_src2, att_src2, W_dst2, att_dst2,
                                       b1, b_lin1, b2, b_lin2,
                                       v_src1, v_dst1, v_src2, v_dst2, bsum1, bsum2);
    pack_kernel<<<256, 256, 0, stream>>>(W_src1, W_lin1, Wp1, 16, HID, 8 * 16 * 512);
    pack_kernel<<<64, 256, 0, stream>>>(W_src2, W_lin2, Wp2, 8, D_OUT, 4 * 8 * 512);

    hipMemsetAsync(deg, 0, (size_t)Nn * 4, stream);
    int eblocks = (E + 255) / 256;
    hist_kernel<<<eblocks, 256, 0, stream>>>(dst, E, deg);
    int nb = (Nn + 1023) / 1024;
    scan_partial<<<nb, 1024, 0, stream>>>(deg, Nn, bsums);
    scan_offsets<<<1, 64, 0, stream>>>(bsums, nb, boff);
    scan_final<<<nb, 1024, 0, stream>>>(deg, Nn, boff, row_ptr, cursor);
    scatter_kernel<<<eblocks, 256, 0, stream>>>(src, dst, E, cursor, ssrc);

    int mblocks = (Nn + 63) / 64;   // 782
    gemm_t<8, 4, true, true><<<mblocks, 256, 0, stream>>>(x, Wp1, bsum1, v_src1, v_dst1,
                                                          a_src1, a_dst1, h1b, lin1b, Nn);

    int ablocks = (Nn + 3) / 4;
    agg1_kernel<<<ablocks, 256, 0, stream>>>(row_ptr, ssrc, a_src1, a_dst1, h1b, lin1b,
                                             v_src2, v_dst2, hb, a_src2, a_dst2, Nn);

    gemm_t<4, 2, false, false><<<mblocks, 256, 0, stream>>>(hb, Wp2, bsum2, nullptr, nullptr,
                                                            nullptr, nullptr, h2b, lin2b, Nn);
    agg2_kernel<<<ablocks, 256, 0, stream>>>(row_ptr, ssrc, a_src2, a_dst2, h2b, lin2b,
                                             out, sminv, Nn);
    alpha_kernel<<<eblocks, 256, 0, stream>>>(src, dst, a_src2, a_dst2, sminv, alpha_out, E);
}